// Round 10
// baseline (1324.427 us; speedup 1.0000x reference)
//
#include <hip/hip_runtime.h>
#include <hip/hip_bf16.h>

#define DIM 512
#define HEADS 8
#define DH 64
#define LM 256
#define NF 8192
#define BHN 16   // batch(2) * heads(8)

typedef __attribute__((ext_vector_type(8))) short short8;
typedef __attribute__((ext_vector_type(4))) float f32x4;

__device__ __forceinline__ float bf2f(unsigned short u) {
  return __uint_as_float((unsigned)u << 16);
}
__device__ __forceinline__ unsigned short f2bf(float x) {
  unsigned u = __float_as_uint(x);
  unsigned r = u + 0x7fffu + ((u >> 16) & 1u);
  return (unsigned short)(r >> 16);
}

// async global->LDS, 16B per lane; lds dest = wave-uniform base + lane*16
__device__ __forceinline__ void gl2lds16(const void* g, void* l) {
  __builtin_amdgcn_global_load_lds(
      (const __attribute__((address_space(1))) void*)g,
      (__attribute__((address_space(3))) void*)l, 16, 0, 0);
}

// LDS-only fence: wait ds ops, then block scheduler from hoisting MFMAs
// above the wait (rule: inline-asm lgkmcnt needs a following sched_barrier).
__device__ __forceinline__ void lds_fence() {
  asm volatile("s_waitcnt lgkmcnt(0)" ::: "memory");
  __builtin_amdgcn_sched_barrier(0);
}

// ---------------- reduction helpers ----------------
__device__ __forceinline__ float waveReduceSum(float v) {
#pragma unroll
  for (int o = 1; o < 64; o <<= 1) v += __shfl_xor(v, o);
  return v;
}
__device__ __forceinline__ float waveReduceMax(float v) {
#pragma unroll
  for (int o = 1; o < 64; o <<= 1) v = fmaxf(v, __shfl_xor(v, o));
  return v;
}
__device__ __forceinline__ float blockReduceSum256(float v, float* sm) {
  v = waveReduceSum(v);
  int w = threadIdx.x >> 6;
  __syncthreads();
  if ((threadIdx.x & 63) == 0) sm[w] = v;
  __syncthreads();
  return sm[0] + sm[1] + sm[2] + sm[3];
}
__device__ __forceinline__ float blockReduceMax256(float v, float* sm) {
  v = waveReduceMax(v);
  int w = threadIdx.x >> 6;
  __syncthreads();
  if ((threadIdx.x & 63) == 0) sm[w] = v;
  __syncthreads();
  return fmaxf(fmaxf(sm[0], sm[1]), fmaxf(sm[2], sm[3]));
}

// ---------------- casts ----------------
__global__ __launch_bounds__(256)
void cvt_bf16(const float* __restrict__ in, unsigned short* __restrict__ out,
              long long n) {
  long long i = ((long long)blockIdx.x * 256 + threadIdx.x) * 4;
  if (i + 3 < n) {
    float4 v = *(const float4*)&in[i];
    ushort4 o;
    o.x = f2bf(v.x); o.y = f2bf(v.y); o.z = f2bf(v.z); o.w = f2bf(v.w);
    *(ushort4*)&out[i] = o;
  } else {
    for (; i < n; i++) out[i] = f2bf(in[i]);
  }
}

// transpose+cast: in fp32 [K][N] -> out bf16 [N][K]
__global__ __launch_bounds__(256)
void cvt_transpose(const float* __restrict__ in, unsigned short* __restrict__ out,
                   int Kd, int Nd) {
  __shared__ float t[32][33];
  int x = threadIdx.x & 31, y = threadIdx.x >> 5;
#pragma unroll
  for (int i = 0; i < 32; i += 8) {
    int k = blockIdx.y * 32 + y + i, n = blockIdx.x * 32 + x;
    t[y + i][x] = in[(long long)k * Nd + n];
  }
  __syncthreads();
#pragma unroll
  for (int i = 0; i < 32; i += 8) {
    int n = blockIdx.x * 32 + y + i, k = blockIdx.y * 32 + x;
    out[(long long)n * Kd + k] = f2bf(t[x][y + i]);
  }
}

// VB [bh][n][d] bf16 -> VT [bh][d][n] bf16
__global__ __launch_bounds__(256)
void vt_transpose(const unsigned short* __restrict__ VB,
                  unsigned short* __restrict__ VT) {
  __shared__ unsigned short t[64][80];
  int bh = blockIdx.x >> 7, tile = blockIdx.x & 127;
  int n0 = tile * 64;
  int tid = threadIdx.x;
#pragma unroll
  for (int it = 0; it < 2; it++) {
    int s = it * 256 + tid;
    int nl = s >> 3, sg = s & 7;
    *(short8*)&t[nl][sg * 8] =
        *(const short8*)&VB[((long long)bh * NF + n0 + nl) * DH + sg * 8];
  }
  __syncthreads();
#pragma unroll
  for (int it = 0; it < 2; it++) {
    int s = it * 256 + tid;
    int dl = s >> 3, sg = s & 7;
    short8 v;
#pragma unroll
    for (int j = 0; j < 8; j++) ((unsigned short*)&v)[j] = t[sg * 8 + j][dl];
    *(short8*)&VT[((long long)bh * DH + dl) * NF + n0 + sg * 8] = v;
  }
}

// ---------------- cls row write ----------------
__global__ __launch_bounds__(256) void write_cls(const float* __restrict__ cls,
                                                 float* __restrict__ X) {
  int t = blockIdx.x * 256 + threadIdx.x;
  int b = t >> 9, c = t & 511;
  X[(long long)b * NF * DIM + c] = cls[c];
}

// ---------------- bf16 MFMA GEMM (projections) ----------------------------
// r10: LDS-BW fix. A-fragments load DIRECTLY global->VGPR (L2-hot via XCD
// swizzle) with register double-buffer; LDS carries B only (3-buf counted
// vmcnt pipeline). LDS traffic/block-step: 48KB -> 24KB (was the binding
// port limit: ~1500cy/CU LDS vs 310cy MFMA).
#define MG_RELU 1
#define MG_ADDC 2
#define MG_BIAS 4
// remap: 0 plain fp32, 1 embed scatter fp32, 2 qkv -> bf16 QB/KB/VB (vector)
__global__ __launch_bounds__(256)
void gemm_mfma(const unsigned short* __restrict__ A,
               const unsigned short* __restrict__ B,
               const float* __restrict__ bias, float* __restrict__ C,
               unsigned short* __restrict__ qkv, unsigned short* __restrict__ vbuf,
               int M, int N, int K, int flags, int remap) {
  __shared__ short8 smem[1536];  // 24 KB: 3 x B(8KB)
  const int tid = threadIdx.x;
  const int lane = tid & 63, wave = tid >> 6;
  const int wm = wave >> 1, wn = wave & 1;
  const int nwg = gridDim.x * gridDim.y;
  const int orig = blockIdx.y * gridDim.x + blockIdx.x;
  const int swz = ((nwg & 7) == 0) ? (orig & 7) * (nwg >> 3) + (orig >> 3) : orig;
  const int m0 = (swz / gridDim.x) * 128, n0 = (swz % gridDim.x) * 128;
  const int r16 = lane & 15, quad = lane >> 4;
  // A direct per-fragment pointers (lane: row=r16, k-off=quad*8)
  const unsigned short* pA[4];
#pragma unroll
  for (int mt = 0; mt < 4; mt++)
    pA[mt] = A + (long long)(m0 + wm * 64 + mt * 16 + r16) * K + quad * 8;
  const unsigned short* pb0 = B + (long long)(n0 + 32 * wave + r16) * K + quad * 8;
  const unsigned short* pb1 = B + (long long)(n0 + 32 * wave + 16 + r16) * K + quad * 8;
  auto stageB = [&](int bsel) {
    short8 (*Bls)[64] = (short8 (*)[64])(smem + bsel * 512);
    gl2lds16(pb0, &Bls[2 * wave][0]);
    gl2lds16(pb1, &Bls[2 * wave + 1][0]);
    pb0 += 32; pb1 += 32;
  };
  f32x4 acc[4][4] = {};
  const int nsteps = K >> 5;  // >= 3 always (16 or 32)
  short8 afC[4], afN[4];
  // prologue: afC first (so compiler's afC-wait leaves B(1) in flight),
  // then B(0), B(1).
#pragma unroll
  for (int mt = 0; mt < 4; mt++) { afC[mt] = *(const short8*)pA[mt]; pA[mt] += 32; }
  stageB(0);
  stageB(1);
  // outstanding: afC(4) B0(2) B1(2); wait afC+B0 done, B1 in flight.
  asm volatile("s_waitcnt vmcnt(2)" ::: "memory");
  __builtin_amdgcn_sched_barrier(0);
  __builtin_amdgcn_s_barrier();
  for (int t = 0; t < nsteps; t++) {
    if (t + 1 < nsteps) {
#pragma unroll
      for (int mt = 0; mt < 4; mt++) { afN[mt] = *(const short8*)pA[mt]; pA[mt] += 32; }
    }
    if (t + 2 < nsteps) stageB((t + 2) % 3);
    short8 (*Bls)[64] = (short8 (*)[64])(smem + (t % 3) * 512);
    short8 bfr[4];
#pragma unroll
    for (int nt = 0; nt < 4; nt++) bfr[nt] = Bls[wn * 4 + nt][lane];
#pragma unroll
    for (int mt = 0; mt < 4; mt++)
#pragma unroll
      for (int nt = 0; nt < 4; nt++)
        acc[mt][nt] = __builtin_amdgcn_mfma_f32_16x16x32_bf16(
            afC[mt], bfr[nt], acc[mt][nt], 0, 0, 0);
#pragma unroll
    for (int mt = 0; mt < 4; mt++) afC[mt] = afN[mt];
    // wait B(t+1) landed; afN + B(t+2) may remain in flight.
    if (t + 2 < nsteps) {
      asm volatile("s_waitcnt vmcnt(6)" ::: "memory");   // afN4 + Bt2(2) fly
    } else if (t + 1 < nsteps) {
      asm volatile("s_waitcnt vmcnt(4)" ::: "memory");   // afN4 fly
    } else {
      asm volatile("s_waitcnt vmcnt(0)" ::: "memory");
    }
    __builtin_amdgcn_sched_barrier(0);
    __builtin_amdgcn_s_barrier();
  }
  if (remap == 2) {
    // Ep aliases the staging memory (safe: final barrier drained all reads)
    unsigned short (*Ep)[32][64] = (unsigned short (*)[32][64])smem;
    int gn_base = n0 + wn * 64;
    int s = gn_base >> 9, hh = (gn_base >> 6) & 7;
    float scale = (s == 0) ? 0.125f : 1.f;
    unsigned short* basep =
        (s == 0) ? qkv : (s == 1) ? qkv + (long long)BHN * NF * DH : vbuf;
#pragma unroll
    for (int half = 0; half < 2; half++) {
      lds_fence();  // prior half's Ep reads drained (wave-local region)
#pragma unroll
      for (int mt = half * 2; mt < half * 2 + 2; mt++)
#pragma unroll
        for (int nt = 0; nt < 4; nt++)
#pragma unroll
          for (int r = 0; r < 4; r++)
            Ep[wave][(mt & 1) * 16 + quad * 4 + r][nt * 16 + r16] =
                f2bf(acc[mt][nt][r] * scale);
      lds_fence();
#pragma unroll
      for (int it = 0; it < 4; it++) {
        int idx = it * 64 + lane;
        int m_l = idx >> 3, sg = idx & 7;
        int gm = m0 + wm * 64 + half * 32 + m_l;
        int b = gm >> 13, n = gm & (NF - 1);
        int bh = b * HEADS + hh;
        short8 v = *(short8*)&Ep[wave][m_l][sg * 8];
        *(short8*)&basep[((long long)bh * NF + n) * DH + sg * 8] = v;
      }
    }
  } else {
#pragma unroll
    for (int mt = 0; mt < 4; mt++) {
#pragma unroll
      for (int nt = 0; nt < 4; nt++) {
#pragma unroll
        for (int r = 0; r < 4; r++) {
          int gm = m0 + wm * 64 + mt * 16 + quad * 4 + r;
          int gn = n0 + wn * 64 + nt * 16 + r16;
          if (gm >= M) continue;
          float v = acc[mt][nt][r];
          if (flags & MG_BIAS) v += bias[gn];
          long long idx;
          if (remap == 1) {
            int b = gm / 8191;
            int n = gm - b * 8191;
            idx = ((long long)(b * NF + 1 + n)) * DIM + gn;
          } else {
            idx = (long long)gm * N + gn;
          }
          if (flags & MG_ADDC) v += C[idx];
          if (flags & MG_RELU) v = fmaxf(v, 0.f);
          C[idx] = v;
        }
      }
    }
  }
}

// ---------------- fused attn1: LDS-resident K_landmark + Wm ---------------
// K (256x64, 32KB) and Wm (64x256, 32KB) staged ONCE per block via
// global_load_lds with XOR swizzle (LDS[row][c] = G[row][c^(row&7)], 16B
// units) -> all MFMA operands come from conflict-free LDS. 512 thr, 8
// waves x 2 row-tiles; 1 block/CU (98KB LDS). No-max softmax + ones-MFMA
// row sums.
__global__ __launch_bounds__(512)
void flash_attn1(const unsigned short* __restrict__ QB,
                 const unsigned short* __restrict__ KLB,
                 const unsigned short* __restrict__ WmB,
                 const unsigned short* __restrict__ XNC,
                 unsigned short* __restrict__ XNB2) {
  __shared__ unsigned short Klds[LM * DH];     // 32 KB
  __shared__ unsigned short Wlds[DH * LM];     // 32 KB
  __shared__ unsigned short Plds[8][16][136];  // 34 KB
  const int bh = blockIdx.y, b = bh >> 3, hh = bh & 7;
  const int tid = threadIdx.x, lane = tid & 63, wave = tid >> 6;
  const int r16 = lane & 15, quad = lane >> 4;
  const unsigned short* Aq = QB + (long long)bh * NF * DH;
  const unsigned short* Kg = KLB + (long long)bh * LM * DH;
  const unsigned short* Wg = WmB + (long long)bh * DH * LM;
#pragma unroll
  for (int j = 0; j < 4; j++) {  // K: 32 x 1KB units
    int u = j * 8 + wave;
    int s = u * 64 + lane;
    int row = s >> 3, ck = s & 7;
    gl2lds16(Kg + row * DH + ((ck ^ (row & 7)) << 3), (char*)Klds + u * 1024);
  }
#pragma unroll
  for (int j = 0; j < 4; j++) {  // Wm: 32 x 1KB units
    int u = j * 8 + wave;
    int s = u * 64 + lane;
    int row = s >> 5, ck = s & 31;
    gl2lds16(Wg + row * LM + ((ck ^ (row & 7)) << 3), (char*)Wlds + u * 1024);
  }
  __syncthreads();
  short8 ones;
#pragma unroll
  for (int j = 0; j < 8; j++) ((unsigned short*)&ones)[j] = 0x3F80;  // bf16 1.0
#pragma unroll
  for (int rt = 0; rt < 2; rt++) {
    const int m0w = blockIdx.x * 256 + (wave * 2 + rt) * 16;
    short8 af[2];
#pragma unroll
    for (int kc = 0; kc < 2; kc++)
      af[kc] = *(const short8*)&Aq[(long long)(m0w + r16) * DH + kc * 32 + quad * 8];
    f32x4 O[4] = {};
    f32x4 Ls = {};
#pragma unroll
    for (int t = 0; t < 2; t++) {
      int c0 = t * 128;
      f32x4 S[8] = {};
      __builtin_amdgcn_s_setprio(1);
#pragma unroll
      for (int nt = 0; nt < 8; nt++) {
        int kl = c0 + nt * 16 + r16;
#pragma unroll
        for (int kc = 0; kc < 2; kc++) {
          short8 bb = *(const short8*)((const char*)Klds + kl * 128 +
                                       (((kc * 4 + quad) ^ (kl & 7)) << 4));
          S[nt] = __builtin_amdgcn_mfma_f32_16x16x32_bf16(af[kc], bb, S[nt], 0, 0, 0);
        }
      }
      __builtin_amdgcn_s_setprio(0);
#pragma unroll
      for (int nt = 0; nt < 8; nt++)
#pragma unroll
        for (int r = 0; r < 4; r++)
          Plds[wave][quad * 4 + r][nt * 16 + r16] = f2bf(__expf(S[nt][r]));
      lds_fence();
      __builtin_amdgcn_s_setprio(1);
#pragma unroll
      for (int kc = 0; kc < 4; kc++) {
        short8 a = *(short8*)&Plds[wave][r16][kc * 32 + quad * 8];
        Ls = __builtin_amdgcn_mfma_f32_16x16x32_bf16(a, ones, Ls, 0, 0, 0);
#pragma unroll
        for (int nt2 = 0; nt2 < 4; nt2++) {
          int wrow = nt2 * 16 + r16;
          int cu = (c0 >> 3) + kc * 4 + quad;
          short8 bb = *(const short8*)((const char*)Wlds + wrow * 512 +
                                       ((cu ^ (wrow & 7)) << 4));
          O[nt2] = __builtin_amdgcn_mfma_f32_16x16x32_bf16(a, bb, O[nt2], 0, 0, 0);
        }
      }
      __builtin_amdgcn_s_setprio(0);
    }
    float invl[4];
#pragma unroll
    for (int r = 0; r < 4; r++) invl[r] = 1.f / Ls[r];
#pragma unroll
    for (int nt2 = 0; nt2 < 4; nt2++)
#pragma unroll
      for (int r = 0; r < 4; r++) {
        int row = m0w + quad * 4 + r;
        int d = nt2 * 16 + r16;
        long long gi = ((long long)(b * NF + row)) * DIM + hh * DH + d;
        XNB2[gi] = f2bf(O[nt2][r] * invl[r] + bf2f(XNC[gi]));
      }
  }
}

// ---------------- fused attn3: LDS-resident K/V chunk pipeline ------------
// Block = (ks, bh): all 256 landmark rows vs a 512-col KV chunk, processed
// as 4 sub-chunks of 128 with double-buffered K(16KB)+V(16KB) staging
// (m97 pattern). No-max + ones-MFMA math.
__device__ __forceinline__ void stage_kv3(const unsigned short* Kg,
                                          const unsigned short* Vg,
                                          unsigned short* Kb, unsigned short* Vb,
                                          int kv0, int wave, int lane) {
#pragma unroll
  for (int j = 0; j < 2; j++) {
    int u = j * 8 + wave;
    int s = u * 64 + lane;
    int kr = s >> 3, kc = s & 7;
    gl2lds16(Kg + (long long)(kv0 + kr) * DH + ((kc ^ (kr & 7)) << 3),
             (char*)Kb + u * 1024);
    int vr = s >> 4, vc = s & 15;
    gl2lds16(Vg + (long long)vr * NF + kv0 + ((vc ^ (vr & 7)) << 3),
             (char*)Vb + u * 1024);
  }
}

__global__ __launch_bounds__(512)
void flash_attn3(const unsigned short* __restrict__ QLB,
                 const unsigned short* __restrict__ KB,
                 const unsigned short* __restrict__ VT,
                 float* __restrict__ Opart, float* __restrict__ Lpart) {
  __shared__ unsigned short Klds[2][128 * DH];  // 2 x 16 KB
  __shared__ unsigned short Vlds[2][DH * 128];  // 2 x 16 KB
  __shared__ unsigned short Plds[8][16][136];   // 34 KB
  const int ks = blockIdx.x, bh = blockIdx.y;
  const int tid = threadIdx.x, lane = tid & 63, wave = tid >> 6;
  const int r16 = lane & 15, quad = lane >> 4;
  const unsigned short* Aq = QLB + (long long)bh * LM * DH;
  const unsigned short* Kg = KB + (long long)bh * NF * DH;
  const unsigned short* Vg = VT + (long long)bh * DH * NF;
  short8 af2[2][2];
#pragma unroll
  for (int rt = 0; rt < 2; rt++) {
    int m0w = (wave * 2 + rt) * 16;
#pragma unroll
    for (int kc = 0; kc < 2; kc++)
      af2[rt][kc] =
          *(const short8*)&Aq[(long long)(m0w + r16) * DH + kc * 32 + quad * 8];
  }
  short8 ones;
#pragma unroll
  for (int j = 0; j < 8; j++) ((unsigned short*)&ones)[j] = 0x3F80;  // bf16 1.0
  f32x4 O2[2][4] = {};
  f32x4 Ls2[2] = {};
  stage_kv3(Kg, Vg, Klds[0], Vlds[0], ks * 512, wave, lane);
  __syncthreads();
  for (int t = 0; t < 4; t++) {
    int cb = t & 1;
    if (t < 3)
      stage_kv3(Kg, Vg, Klds[cb ^ 1], Vlds[cb ^ 1], ks * 512 + (t + 1) * 128,
                wave, lane);
    const unsigned short* Kb = Klds[cb];
    const unsigned short* Vb = Vlds[cb];
#pragma unroll
    for (int rt = 0; rt < 2; rt++) {
      f32x4 S[8] = {};
      __builtin_amdgcn_s_setprio(1);
#pragma unroll
      for (int nt = 0; nt < 8; nt++) {
        int kl = nt * 16 + r16;
#pragma unroll
        for (int kc = 0; kc < 2; kc++) {
          short8 bb = *(const short8*)((const char*)Kb + kl * 128 +
                                       (((kc * 4 + quad) ^ (kl & 7)) << 4));
          S[nt] = __builtin_amdgcn_mfma_f32_16x16x32_bf16(af2[rt][kc], bb, S[nt],
                                                          0, 0, 0);
        }
      }
      __builtin_amdgcn_s_setprio(0);
#pragma unroll
      for (int nt = 0; nt < 8; nt++)
#pragma unroll
        for (int r = 0; r < 4; r++)
          Plds[wave][quad * 4 + r][nt * 16 + r16] = f2bf(__expf(S[nt][r]));
      lds_fence();
      __builtin_amdgcn_s_setprio(1);
#pragma unroll
      for (int kc2 = 0; kc2 < 4; kc2++) {
        short8 a = *(short8*)&Plds[wave][r16][kc2 * 32 + quad * 8];
        Ls2[rt] = __builtin_amdgcn_mfma_f32_16x16x32_bf16(a, ones, Ls2[rt], 0, 0, 0);
#pragma unroll
        for (int nt2 = 0; nt2 < 4; nt2++) {
          int vr = nt2 * 16 + r16;
          int u = kc2 * 4 + quad;
          short8 bb = *(const short8*)((const char*)Vb + vr * 256 +
                                       ((u ^ (vr & 7)) << 4));
          O2[rt][nt2] = __builtin_amdgcn_mfma_f32_16x16x32_bf16(a, bb, O2[rt][nt2],
                                                                0, 0, 0);
        }
      }
      __builtin_amdgcn_s_setprio(0);
    }
    __syncthreads();
  }
  float* Ob = Opart + (((long long)ks * BHN + bh) * LM) * DH;
#pragma unroll
  for (int rt = 0; rt < 2; rt++) {
    int m0w = (wave * 2 + rt) * 16;
#pragma unroll
    for (int nt2 = 0; nt2 < 4; nt2++)
#pragma unroll
      for (int r = 0; r < 4; r++)
        Ob[(long long)(m0w + quad * 4 + r) * DH + nt2 * 16 + r16] = O2[rt][nt2][r];
    if (r16 == 0)
#pragma unroll
      for (int r = 0; r < 4; r++)
        Lpart[((long long)ks * BHN + bh) * LM + m0w + quad * 4 + r] = Ls2[rt][r];
  }
}

__global__ __launch_bounds__(256)
void attn3_merge(const float* __restrict__ Opart, const float* __restrict__ Lpart,
                 float* __restrict__ O3) {
  int idx = blockIdx.x * 256 + threadIdx.x;  // 262144
  int bh = idx >> 14, rem = idx & 16383;
  int row = rem >> 6, d = rem & 63;
  float L = 0.f, acc = 0.f;
#pragma unroll
  for (int c = 0; c < 16; c++) {
    L += Lpart[((long long)c * BHN + bh) * LM + row];
    acc += Opart[(((long long)c * BHN + bh) * LM + row) * DH + d];
  }
  O3[((long long)bh * LM + row) * DH + d] = acc / L;
}

// ---------------- z0 = attn2^T / rowmax; writes bf16 normal + transposed ---
__global__ __launch_bounds__(256)
void zinit(const float* __restrict__ a2, const unsigned* __restrict__ red,
           unsigned short* __restrict__ zn, unsigned short* __restrict__ zt) {
  // softmax rows sum to 1 exactly => ref's "col" factor == 1; scale = 1/colmax
  float scale = 1.0f / __uint_as_float(red[1]);
  long long idx = (long long)blockIdx.x * 256 + threadIdx.x;
  int bh = (int)(idx >> 16);
  int ij = (int)(idx & 65535);
  int i = ij >> 8, j = ij & 255;
  zn[idx] = f2bf(a2[((long long)bh << 16) + (j << 8) + i] * scale);
  zt[idx] = f2bf(a2[idx] * scale);
}

// ---------------- pinv bf16 GEMM, full-K staging, dual-layout output -------
// C = alpha * (ident * A[m][n] + beta * (A@B)[m][n]); B given TRANSPOSED.
// 32x32 tiles (grid 8x8x16 = 1024 blocks, 4 blocks/CU) for latency overlap.
#define PV_CN 1   // write Cn bf16 [m][n]
#define PV_CT 2   // write Ct bf16 [n][m]
#define PV_CF 4   // write Cf fp32 [m][n]
#define PV_ID 8   // include ident*A[m][n] term (A@I = A)
__global__ __launch_bounds__(256)
void pinv_bf(const unsigned short* __restrict__ An,
             const unsigned short* __restrict__ Bt,
             unsigned short* __restrict__ Cn, unsigned short* __restrict__ Ct,
             float* __restrict__ Cf, float alpha, float ident, float beta,
             int flags) {
  __shared__ unsigned short Als[32][256];  // 16 KB, XOR-swizzled chunks
  __shared__ unsigned short Bls[32][256];
  const int batch = blockIdx.z;
  An += (long long)batch * 65536;
  Bt += (long long)batch * 65536;
  const int tid = threadIdx.x, lane = tid & 63, wave = tid >> 6;
  const int wm2 = wave >> 1, wn2 = wave & 1;
  const int m0 = blockIdx.y * 32, n0 = blockIdx.x * 32;
  const int r16 = lane & 15, quad = lane >> 4;
  // one-shot full-K staging. LDS physical chunk g holds logical k-chunk
  // (g&31)^(row&7) of row g>>5 (pre-swizzled global source, linear LDS dest).
#pragma unroll
  for (int j = 0; j < 4; j++) {
    int g = (j * 4 + wave) * 64 + lane;  // 0..1023
    int row = g >> 5, plog = (g & 31) ^ (row & 7);
    gl2lds16(An + ((m0 + row) << 8) + plog * 8,
             (char*)Als + (j * 4 + wave) * 1024);
    gl2lds16(Bt + ((n0 + row) << 8) + plog * 8,
             (char*)Bls + (j * 4 + wave) * 1024);
  }
  __syncthreads();
  f32x4 acc = {};
  const int arow = wm2 * 16 + r16, brow = wn2 * 16 + r16;
#pragma unroll
  for (int kk = 0; kk < 8; kk++) {
    short8 af = *(const short8*)((const char*)Als + arow * 512 +
                                 ((kk * 4 + quad) ^ (arow & 7)) * 16);
    short8 bfr = *(const short8*)((const char*)Bls + brow * 512 +
                                  ((kk * 4 + quad) ^ (brow & 7)) * 16);
    acc = __builtin_amdgcn_mfma_f32_16x16x32_bf16(af, bfr, acc, 0, 0, 0);
  }
  long long cb = (long long)batch * 65536;
  int ncol = n0 + wn2 * 16 + r16;
  float vals[4];
#pragma unroll
  for (int r = 0; r < 4; r++) {
    int mrow = wm2 * 16 + quad * 4 + r;  // local row in [0,32)
    float v = beta * acc[r];
    if (flags & PV_ID) {
      // A[m][n] read back from the staged (swizzled) A tile
      unsigned short a = *(const unsigned short*)(
          (const char*)Als + mrow * 512 +
          (((ncol >> 3) ^ (mrow & 7)) * 16) + (ncol & 7) * 2);
      v += ident * bf2f(a);
    }
    vals[r] = v * alpha;
    int gm = m0 + mrow;
    if (flags & PV_CN) Cn[cb + ((long long)gm << 8) + ncol] = f2bf(vals[r]);
    if (flags & PV_CF) Cf[cb + ((long long)gm << 8) + ncol] = vals[r];
  }
  if (flags & PV_CT) {
    ushort4 o;
    o.x = f2bf(vals[0]); o.y = f2bf(vals[1]);
    o.z = f2bf(vals[2]); o.w = f2bf(vals[3]);
    *(ushort4*)&Ct[cb + ((long long)ncol << 8) + m0 + wm2 * 16 + quad * 4] = o;
  }
}

// ---------------- batched GEMM (fp32: last pinv iter) ----------------
#define BG_BIDENT 16
__global__ __launch_bounds__(256)
void bgemm(const float* __restrict__ A, const float* __restrict__ B,
           float* __restrict__ C, int M, int N, int K,
           long long sA, long long sB, long long sC,
           float alpha, float ident, int flags) {
  const int batch = blockIdx.z;
  A += (long long)batch * sA;
  B += (long long)batch * sB;
  float* Cb = C + (long long)batch * sC;
  __shared__ float As[16][68];
  __shared__ float Bs[16][68];
  const int tid = threadIdx.x;
  const int tx = tid & 15, ty = tid >> 4;
  const int m0 = blockIdx.y * 64, n0 = blockIdx.x * 64;
  float acc[4][4] = {};
  for (int k0 = 0; k0 < K; k0 += 16) {
    {
      int k = tid & 15;
      int mBase = tid >> 4;
#pragma unroll
      for (int i = 0; i < 4; i++) {
        int m = mBase + i * 16;
        int gm = m0 + m;
        As[k][m] = (gm < M) ? A[(long long)gm * K + (k0 + k)] : 0.f;
      }
    }
    {
      int n = tid & 63;
      int kBase = tid >> 6;
#pragma unroll
      for (int i = 0; i < 4; i++) {
        int k = kBase + i * 4;
        int gn = n0 + n;
        float vb = (gn < N) ? B[(long long)(k0 + k) * N + gn] : 0.f;
        if (flags & BG_BIDENT) vb = ident * ((k0 + k) == gn ? 1.f : 0.f) - vb;
        Bs[k][n] = vb;
      }
    }
    __syncthreads();
#pragma unroll
    for (int k = 0; k < 16; k++) {
      float a[4], b[4];
#pragma unroll
      for (int i = 0; i < 4; i++) a[i] = As[k][ty * 4 + i];
#pragma unroll
      for (int j = 0; j < 4; j++) b[j] = Bs[k][tx * 4 + j];
#pragma unroll
      for (int i = 0; i < 4; i++)
#pragma unroll
        for (int j = 0; j < 4; j++) acc[i][j] = fmaf(a[i], b[j], acc[i][j]);
    }
    __syncthreads();
  }
#pragma unroll
  for (int i = 0; i < 4; i++) {
    int gm = m0 + ty * 4 + i;
    if (gm >= M) continue;
#pragma unroll
    for (int j = 0; j < 4; j++) {
      int gn = n0 + tx * 4 + j;
      if (gn >= N) continue;
      Cb[(long long)gm * N + gn] = alpha * acc[i][j];
    }
  }
}

// ---------------- Wm = z @ O3, written transposed bf16 WmT[bh][d][k] -------
__global__ __launch_bounds__(256)
void wm_gemm(const float* __restrict__ Z, const float* __restrict__ O3,
             unsigned short* __restrict__ WmT) {
  const int batch = blockIdx.y;
  const int m0 = blockIdx.x * 64;
  const float* A = Z + (long long)batch * 65536;
  const float* B = O3 + (long long)batch * LM * DH;
  __shared__ float As[16][68];
  __shared__ float Bs[16][68];
  const int tid = threadIdx.x, tx = tid & 15, ty = tid >> 4;
  float acc[4][4] = {};
  for (int k0 = 0; k0 < 256; k0 += 16) {
    {
      int k = tid & 15, mB = tid >> 4;
#pragma unroll
      for (int i = 0; i < 4; i++) {
        int m = mB + i * 16;
        As[k][m] = A[(long long)(m0 + m) * 256 + k0 + k];
      }
    }
    {
      int n = tid & 63, kB = tid >> 6;
#pragma unroll
      for (int i = 0; i < 4; i++) {
        int k = kB + i * 4;
        Bs[k][n] = B[(long long)(k0 + k) * DH + n];
      }
    }
    __syncthreads();
#pragma unroll
    for (int k = 0; k < 16; k++) {
      float a[4], b[4];
#pragma unroll
      for (int i = 0; i < 4; i++) a[i] = As[k][ty * 4 + i];
#pragma unroll
      for (int j = 0; j < 4; j++) b[j] = Bs[k][tx * 4 + j];
#pragma unroll
      for (int i = 0; i < 4; i++)
#pragma unroll
        for (int j = 0; j < 4; j++) acc[i][j] = fmaf(a[i], b[j], acc[i][j]);
    }
    __syncthreads();
  }
#pragma unroll
  for (int i = 0; i < 4; i++)
#pragma unroll
    for (int j = 0; j < 4; j++)
      WmT[((long long)batch * DH + tx * 4 + j) * LM + m0 + ty * 4 + i] =
          f2bf(acc[i][j]);
}

// ---------------- row layernorm over 512 -> bf16 ----------------
__global__ __launch_bounds__(256)
void layernorm_rows_bf16(const float* __restrict__ X, const float* __restrict__ g,
                         const float* __restrict__ bt,
                         unsigned short* __restrict__ Y) {
  __shared__ float sm[4];
  long long r = blockIdx.x;
  const float* x = X + r * DIM;
  int t = threadIdx.x;
  float v0 = x[t], v1 = x[t + 256];
  float mu = blockReduceSum256(v0 + v1, sm) * (1.f / DIM);
  float d0 = v0 - mu, d1 = v1 - mu;
  float var = blockReduceSum256(d0 * d0 + d1 * d1, sm) * (1.f / DIM);
  float rs = 1.0f / sqrtf(var + 1e-5f);
  unsigned short* y = Y + r * DIM;
  y[t] = f2bf(d0 * rs * g[t] + bt[t]);
  y[t + 256] = f2bf(d1 * rs * g[t + 256] + bt[t + 256]);
}

// ---------------- landmark means from bf16 q,k ----------------
__global__ __launch_bounds__(64)
void landmarks_k(const unsigned short* __restrict__ q,
                 const unsigned short* __restrict__ k,
                 float* __restrict__ ql, float* __restrict__ kl,
                 unsigned short* __restrict__ qlb,
                 unsigned short* __restrict__ klb) {
  int bh = blockIdx.x >> 8, i = blockIdx.x & 255, d = threadIdx.x;
  long long base = ((long long)bh * NF + i * 32) * DH + d;
  float sq = 0.f, sk = 0.f;
#pragma unroll 4
  for (int l = 0; l < 32; l++) {
    sq += bf2f(q[base + (long long)l * DH]);
    sk += bf2f(k[base + (long long)l * DH]);
  }
  long long o = ((long long)bh * LM + i) * DH + d;
  float mq = sq * (1.f / 32.f), mk = sk * (1.f / 32.f);
  ql[o] = mq; kl[o] = mk;
  qlb[o] = f2bf(mq); klb[o] = f2bf(mk);
}

// ---------------- sim2 + row softmax -> attn2 (fp32 + bf16) ----------------
__global__ __launch_bounds__(256)
void sim2_softmax(const float* __restrict__ ql, const float* __restrict__ kl,
                  float* __restrict__ a2, unsigned short* __restrict__ a2b) {
  __shared__ float qs[64];
  __shared__ float sm[4];
  int bh = blockIdx.x >> 8, i = blockIdx.x & 255, t = threadIdx.x;
  if (t < 64) qs[t] = ql[((long long)bh * LM + i) * DH + t];
  __syncthreads();
  const float* krow = kl + (long long)bh * LM * DH + (long long)t * DH;
  float s = 0.f;
#pragma unroll
  for (int d = 0; d < 64; d++) s += qs[d] * krow[d];
  float m = blockReduceMax256(s, sm);
  float e = expf(s - m);
  float sum = blockReduceSum256(e, sm);
  long long off = ((long long)bh * LM + i) * LM + t;
  float v = e / sum;
  a2[off] = v;
  a2b[off] = f2bf(v);
}

// ---------------- pinv global scale reduction (col sums only) --------------
// softmax rows sum to exactly 1 -> the ref's row-sum max factor == 1.
__global__ __launch_bounds__(256)
void pinv_reduce(const float* __restrict__ a2, unsigned* __restrict__ red) {
  __shared__ float sm[4];
  int bh = blockIdx.x, t = threadIdx.x;
  const float* A = a2 + (long long)bh * LM * LM;
  float cs = 0.f;
  for (int i = 0; i < 256; i++) cs += fabsf(A[i * 256 + t]);
  float cm = blockReduceMax256(cs, sm);
  if (t == 0) atomicMax(&red[1], __float_as_uint(cm));
}

// ---------------- depthwise conv residual -> bf16 scattered ----------------
__global__ __launch_bounds__(256)
void conv_res_bf16(const unsigned short* __restrict__ vt,
                   const float* __restrict__ cw,
                   unsigned short* __restrict__ out) {
  int bh = blockIdx.x >> 6, tile = blockIdx.x & 63;
  int b = bh >> 3, hh = bh & 7;
  int t = threadIdx.x;
  int d = t & 63, pg = t >> 6;
  float wr[33];
#pragma unroll
  for (int kk = 0; kk < 33; kk++) wr[kk] = cw[hh * 33 + kk];
  const unsigned short* src = &vt[((long long)bh * DH + d) * NF];
  int base = tile * 128 + pg * 32;
  int n0 = base - 16;
  float win[64];
#pragma unroll
  for (int jj = 0; jj < 8; jj++) {
    int c = n0 + jj * 8;
    if (c >= 0 && c + 7 < NF) {
      short8 v = *(const short8*)&src[c];
#pragma unroll
      for (int j = 0; j < 8; j++)
        win[jj * 8 + j] = bf2f((unsigned short)v[j]);
    } else {
#pragma unroll
      for (int j = 0; j < 8; j++) {
        int nn = c + j;
        win[jj * 8 + j] = (nn >= 0 && nn < NF) ? bf2f(src[nn]) : 0.f;
      }
    }
  }
  unsigned short* dst = &out[((long long)(b * NF + base)) * DIM + hh * DH + d];
#pragma unroll
  for (int p = 0; p < 32; p++) {
    float s = 0.f;
#pragma unroll
    for (int kk = 0; kk < 33; kk++) s = fmaf(wr[kk], win[p + kk], s);
    dst[(long long)p * DIM] = f2bf(s);
  }
}

// ---------------- final LN(row0) @ w2 + b2 ----------------
__global__ __launch_bounds__(256)
void final_head(const float* __restrict__ X, const float* __restrict__ g,
                const float* __restrict__ bt, const float* __restrict__ w2,
                const float* __restrict__ b2, float* __restrict__ out) {
  __shared__ float sm[4];
  int b = blockIdx.x, t = threadIdx.x;
  const float* row = X + (long long)b * NF * DIM;
  float v0 = row[t], v1 = row[t + 256];
  float mu = blockReduceSum256(v0 + v1, sm) * (1.f / DIM);
  float d0 = v0 - mu, d1 = v1 - mu;
  float var = blockReduceSum256(d0 * d0 + d1 * d1, sm) * (1.f / DIM);
  float rs = 1.0f / sqrtf(var + 1e-5f);
  float y0 = d0 * rs * g[t] + bt[t];
  float y1 = d1 * rs * g[t + 256] + bt[t + 256];
  float l0 = y0 * w2[t * 2 + 0] + y1 * w2[(t + 256) * 2 + 0];
  float l1 = y0 * w2[t * 2 + 1] + y1 * w2[(t + 256) * 2 + 1];
  l0 = blockReduceSum256(l0, sm);
  l1 = blockReduceSum256(l1, sm);
  if (t == 0) {
    out[b * 2 + 0] = l0 + b2[0];
    out[b * 2 + 1] = l1 + b2[1];
  }
}

extern "C" void kernel_launch(void* const* d_in, const int* in_sizes, int n_in,
                              void* d_out, int out_size, void* d_ws,
                              size_t ws_size, hipStream_t stream) {
  const float* h      = (const float*)d_in[0];
  const float* w1     = (const float*)d_in[1];
  const float* b1     = (const float*)d_in[2];
  const float* cls    = (const float*)d_in[3];
  const float* ln_g   = (const float*)d_in[4];
  const float* ln_b   = (const float*)d_in[5];
  const float* w_qkv  = (const float*)d_in[6];
  const float* w_out  = (const float*)d_in[7];
  const float* b_out  = (const float*)d_in[8];
  const float* conv_w = (const float*)d_in[9];
  const float* fn_g   = (const float*)d_in[10];
  const float* fn_b   = (const float*)d_in[11];
  const float* w2     = (const float*)d_in[12];
  const float* b2     = (const float*)d_in[13];

  float* ws = (float*)d_ws;
  const long long XSZ = (long long)2 * NF * DIM;      // 8388608
  const long long QSZ = (long long)BHN * NF * DH;     // 8388608
  float* X  = ws;                                     // 8.4M f
  unsigned short* STAGE = (unsigned short*)(X + XSZ); // staging us region
  unsigned short* HB   = STAGE;                 // embed bf16
  unsigned short* XNB1 = STAGE;                 // LN out bf16
  unsigned short* XNB2 = STAGE;                 // attn out bf16 (XNB1 dead)
  unsigned short* VB   = STAGE + XSZ;           // V row-major temp
  unsigned short* XNC  = STAGE + XSZ;           // conv bf16 (VB dead)
  unsigned short* QB = STAGE + 2 * XSZ;
  unsigned short* KB = QB + QSZ;
  unsigned short* VT = KB + QSZ;                // d-major
  float* QL = (float*)(VT + QSZ);
  float* KL = QL + 262144;
  unsigned short* QLB = (unsigned short*)(KL + 262144);
  unsigned short* KLB = QLB + 262144;
  float* A2 = (float*)(KLB + 262144);           // fp32 attn2 (reduce + it5)
  float* ZA = A2 + 1048576;                     // final fp32 z (wm_gemm)
  float* ZB = ZA + 1048576;                     // z4 fp32 (it5 input)
  float* P  = ZB + 1048576;                     // it5 fp32 temps
  float* T1 = P + 1048576;
  float* T2 = T1 + 1048576;
  float* Mpart = T2 + 1048576;                  // 65536 f (unused slot)
  float* Lpart = Mpart + 65536;                 // 65536 f
  float* O3 = Lpart + 65536;                    // 262144 f
  unsigned short* WmB = (unsigned short*)(O3 + 262144);  // 262144 us
  unsigned* RED = (unsigned*)(WmB + 262144);    // [unused, colmax, pad, pad]
  unsigned short* WT = (unsigned short*)(RED + 4);
  unsigned short* W1T = WT;                     // 524288 us
  unsigned short* WQ0 = W1T + 524288;           // 786432
  unsigned short* WQ1 = WQ0 + 786432;           // 786432
  unsigned short* WO0 = WQ1 + 786432;           // 262144
  unsigned short* WO1 = WO0 + 262144;           // 262144

  // Aliases with disjoint liveness inside the VB/XNC slot (16.77 MB):
  //   VB (qkv->vt) -> A2B (sim2->pinv it4 S1) -> Opart (attn3->merge) -> XNC
  unsigned short* A2B = VB;                     // bf16 attn2 (pinv A-operand)
  float* Opart = (float*)VB;                    // 16*16*256*64 f = 16.77 MB
  // bf16 pinv buffers alias fp32 it5 temps (live only during it0..4):
  unsigned short* Zan = (unsigned short*)P;     // z even-iter (normal)
  unsigned short* Zat = Zan + 1048576;          // z even-iter (transposed)
  unsigned short* Zbn = (unsigned short*)ZB;    // z odd-iter
  unsigned short* Zbt = Zbn + 1048576;
  unsigned short* Pn  = (unsigned short*)T1;    // P = A2@z
  unsigned short* Pt  = Pn + 1048576;
  unsigned short* T1t = (unsigned short*)T2;    // bracket temps (B-operand only)
  unsigned short* T2t = T1t + 1048576;

  // ---- prologue: cls, h cast, all weight transposes, embed ----
  write_cls<<<4, 256, 0, stream>>>(cls, X);
  cvt_bf16<<<16382, 256, 0, stream>>>(h, HB, (long long)16382 * 1024);
  cvt_transpose<<<dim3(512 / 32, 1024 / 32), 256, 0, stream>>>(w1, W1T, 1024, 512);
  cvt_transpose<<<dim3(1536 / 32, 512 / 32), 256, 0, stream>>>(w_qkv, WQ0, 512, 1536);
  cvt_transpose<<<dim3(1536 / 32, 512 / 32), 256, 0, stream>>>(
      w_qkv + (long long)DIM * 1536, WQ1, 512, 1536);
  cvt_transpose<<<dim3(512 / 32, 512 / 32), 256, 0, stream>>>(w_out, WO0, 512, 512);
  cvt_transpose<<<dim3(512 / 32, 512 / 32), 256, 0, stream>>>(
      w_out + (long long)DIM * DIM, WO1, 512, 512);
  gemm_mfma<<<dim3(4, 128), 256, 0, stream>>>(HB, W1T, b1, X, nullptr, nullptr,
                                              16382, 512, 1024, MG_RELU | MG_BIAS, 1);

  for (int L = 0; L < 2; L++) {
    layernorm_rows_bf16<<<2 * NF, 256, 0, stream>>>(X, ln_g + L * DIM,
                                                    ln_b + L * DIM, XNB1);
    gemm_mfma<<<dim3(12, 128), 256, 0, stream>>>(XNB1, L ? WQ1 : WQ0, nullptr,
                                                 nullptr, QB, VB, 16384, 1536,
                                                 512, 0, 2);
    vt_transpose<<<BHN * 128, 256, 0, stream>>>(VB, VT);

    landmarks_k<<<BHN * LM, 64, 0, stream>>>(QB, KB, QL, KL, QLB, KLB);
    sim2_softmax<<<BHN * LM, 256, 0, stream>>>(QL, KL, A2, A2B);
    hipMemsetAsync(RED, 0, 16, stream);
    pinv_reduce<<<BHN, 256, 0, stream>>>(A2, RED);
    zinit<<<4096, 256, 0, stream>>>(A2, RED, Zan, Zat);
    for (int it = 0; it < 5; it++) {  // bf16 iterations (NS self-corrects)
      const unsigned short* zcn = (it & 1) ? Zbn : Zan;
      const unsigned short* zct = (it & 1) ? Zbt : Zat;
      unsigned short* znn = (it & 1) ? Zan : Zbn;
      unsigned short* znt = (it & 1) ? Zat : Zbt;
      // P = A2 @ z
      pinv_bf<<<dim3(8, 8, BHN), 256, 0, stream>>>(
          A2B, zct, Pn, Pt, nullptr, 1.f, 0.f, 1.f, PV_CN | PV_CT);
      // T1 = 7P - P@P
      pinv_bf<<<dim3(8, 8, BHN), 256, 0, stream>>>(
          Pn, Pt, nullptr, T1t, nullptr, 1.f, 7.f, -1.f, PV_CT | PV_ID);
      // T2 = 15P - P@T1
      pinv_bf<<<dim3(8, 8, BHN), 256, 0, stream>>>(
          Pn, T1t, nullptr, T2t, nullptr, 1.f, 15.f, -1.f, PV_CT | PV_ID);
      // zn = 0.25*(13z - z@T2); it==4 writes fp32 z4 for the fp32 iteration
      if (it < 4)
        pinv_bf<<<dim3(8, 8, BHN), 256, 0, stream>>>(
            zcn, T2t, znn, znt, nullptr, 0.25f, 13.f, -1.f,
            PV_CN | PV_CT | PV_ID);
      else
        pinv_bf<<<dim3(8, 8, BHN), 256, 0, stream>>>(
            zcn, T2t, nullptr, nullptr, ZB, 0.25f, 13.f, -1.f, PV_CF | PV_ID);
    }
    // final iteration fp32
    bgemm<<<dim3(4, 4, BHN), 256, 0, stream>>>(A2, ZB, P, 256, 256, 256,
                                               65536, 65536, 65536, 1.f, 0.f, 0);
    bgemm<<<dim3(4, 4, BHN), 256, 0, stream>>>(P, P, T1, 256, 256, 256,
                                               65536, 65536, 65536, 1.f, 7.f,
                                               BG_BIDENT);
    bgemm<<<dim3(4, 4, BHN), 256, 0, stream>>>(P, T1, T2, 256, 256, 256,
                                               65536, 65536, 65536, 1.f, 15.f,
                                               BG_BIDENT);
    bgemm<<<dim3(4, 4, BHN), 256, 0, stream>>>(ZB, T2, ZA, 256, 256, 256,
                                               65536, 65536, 65536, 0.25f,
                                               13.f, BG_BIDENT);
    // final z in ZA

    // ---- fused attn3: LDS-resident chunks; plain (O,L) partials -> O3 ----
    flash_attn3<<<dim3(16, BHN), 512, 0, stream>>>(QLB, KB, VT, Opart, Lpart);
    attn3_merge<<<1024, 256, 0, stream>>>(Opart, Lpart, O3);

    // WmT(bf16) = (z @ O3)^T
    wm_gemm<<<dim3(4, BHN), 256, 0, stream>>>(ZA, O3, WmB);

    // conv residual (bf16) into XNC (overwrites dead Opart)
    conv_res_bf16<<<BHN * 64, 256, 0, stream>>>(VT, conv_w + L * 264, XNC);

    // ---- fused attn1 (LDS-resident K+Wm): XNB2 = bf16(conv + attn1@Wm) ----
    flash_attn1<<<dim3(32, BHN), 512, 0, stream>>>(QB, KLB, WmB, XNC, XNB2);

    // ---- X += XNB2 @ w_out + b_out ----
    gemm_mfma<<<dim3(4, 128), 256, 0, stream>>>(XNB2, L ? WO1 : WO0,
                                                b_out + L * DIM, X, nullptr,
                                                nullptr, 16384, 512, 512,
                                                MG_ADDC | MG_BIAS, 0);
  }
  final_head<<<2, 256, 0, stream>>>(X, fn_g, fn_b, w2, b2, (float*)d_out);
}

// Round 11
// 1247.326 us; speedup vs baseline: 1.0618x; 1.0618x over previous
//
#include <hip/hip_runtime.h>
#include <hip/hip_bf16.h>

#define DIM 512
#define HEADS 8
#define DH 64
#define LM 256
#define NF 8192
#define BHN 16   // batch(2) * heads(8)

typedef __attribute__((ext_vector_type(8))) short short8;
typedef __attribute__((ext_vector_type(4))) float f32x4;

__device__ __forceinline__ float bf2f(unsigned short u) {
  return __uint_as_float((unsigned)u << 16);
}
__device__ __forceinline__ unsigned short f2bf(float x) {
  unsigned u = __float_as_uint(x);
  unsigned r = u + 0x7fffu + ((u >> 16) & 1u);
  return (unsigned short)(r >> 16);
}

// async global->LDS, 16B per lane; lds dest = wave-uniform base + lane*16
__device__ __forceinline__ void gl2lds16(const void* g, void* l) {
  __builtin_amdgcn_global_load_lds(
      (const __attribute__((address_space(1))) void*)g,
      (__attribute__((address_space(3))) void*)l, 16, 0, 0);
}

// LDS-only fence: wait ds ops, then block scheduler from hoisting MFMAs
// above the wait (rule: inline-asm lgkmcnt needs a following sched_barrier).
__device__ __forceinline__ void lds_fence() {
  asm volatile("s_waitcnt lgkmcnt(0)" ::: "memory");
  __builtin_amdgcn_sched_barrier(0);
}

// ---------------- reduction helpers ----------------
__device__ __forceinline__ float waveReduceSum(float v) {
#pragma unroll
  for (int o = 1; o < 64; o <<= 1) v += __shfl_xor(v, o);
  return v;
}
__device__ __forceinline__ float waveReduceMax(float v) {
#pragma unroll
  for (int o = 1; o < 64; o <<= 1) v = fmaxf(v, __shfl_xor(v, o));
  return v;
}
__device__ __forceinline__ float blockReduceSum256(float v, float* sm) {
  v = waveReduceSum(v);
  int w = threadIdx.x >> 6;
  __syncthreads();
  if ((threadIdx.x & 63) == 0) sm[w] = v;
  __syncthreads();
  return sm[0] + sm[1] + sm[2] + sm[3];
}
__device__ __forceinline__ float blockReduceMax256(float v, float* sm) {
  v = waveReduceMax(v);
  int w = threadIdx.x >> 6;
  __syncthreads();
  if ((threadIdx.x & 63) == 0) sm[w] = v;
  __syncthreads();
  return fmaxf(fmaxf(sm[0], sm[1]), fmaxf(sm[2], sm[3]));
}

// ---------------- casts ----------------
__global__ __launch_bounds__(256)
void cvt_bf16(const float* __restrict__ in, unsigned short* __restrict__ out,
              long long n) {
  long long i = ((long long)blockIdx.x * 256 + threadIdx.x) * 4;
  if (i + 3 < n) {
    float4 v = *(const float4*)&in[i];
    ushort4 o;
    o.x = f2bf(v.x); o.y = f2bf(v.y); o.z = f2bf(v.z); o.w = f2bf(v.w);
    *(ushort4*)&out[i] = o;
  } else {
    for (; i < n; i++) out[i] = f2bf(in[i]);
  }
}

// transpose+cast: in fp32 [K][N] -> out bf16 [N][K]
__global__ __launch_bounds__(256)
void cvt_transpose(const float* __restrict__ in, unsigned short* __restrict__ out,
                   int Kd, int Nd) {
  __shared__ float t[32][33];
  int x = threadIdx.x & 31, y = threadIdx.x >> 5;
#pragma unroll
  for (int i = 0; i < 32; i += 8) {
    int k = blockIdx.y * 32 + y + i, n = blockIdx.x * 32 + x;
    t[y + i][x] = in[(long long)k * Nd + n];
  }
  __syncthreads();
#pragma unroll
  for (int i = 0; i < 32; i += 8) {
    int n = blockIdx.x * 32 + y + i, k = blockIdx.y * 32 + x;
    out[(long long)n * Kd + k] = f2bf(t[x][y + i]);
  }
}

// VB [bh][n][d] bf16 -> VT [bh][d][n] bf16
__global__ __launch_bounds__(256)
void vt_transpose(const unsigned short* __restrict__ VB,
                  unsigned short* __restrict__ VT) {
  __shared__ unsigned short t[64][80];
  int bh = blockIdx.x >> 7, tile = blockIdx.x & 127;
  int n0 = tile * 64;
  int tid = threadIdx.x;
#pragma unroll
  for (int it = 0; it < 2; it++) {
    int s = it * 256 + tid;
    int nl = s >> 3, sg = s & 7;
    *(short8*)&t[nl][sg * 8] =
        *(const short8*)&VB[((long long)bh * NF + n0 + nl) * DH + sg * 8];
  }
  __syncthreads();
#pragma unroll
  for (int it = 0; it < 2; it++) {
    int s = it * 256 + tid;
    int dl = s >> 3, sg = s & 7;
    short8 v;
#pragma unroll
    for (int j = 0; j < 8; j++) ((unsigned short*)&v)[j] = t[sg * 8 + j][dl];
    *(short8*)&VT[((long long)bh * DH + dl) * NF + n0 + sg * 8] = v;
  }
}

// ---------------- cls row write ----------------
__global__ __launch_bounds__(256) void write_cls(const float* __restrict__ cls,
                                                 float* __restrict__ X) {
  int t = blockIdx.x * 256 + threadIdx.x;
  int b = t >> 9, c = t & 511;
  X[(long long)b * NF * DIM + c] = cls[c];
}

// ---------------- bf16 MFMA GEMM (projections) ----------------------------
// r11: 128x256 tile, 8 waves (2x4), 2-buffer gl2lds pipeline (r8 proven).
// LDS traffic per MFMA: 344B (was 750 at 128x128) -> crosses over to
// MFMA-bound (r9 analysis: LDS port was the limit at ~1400cy/step).
// XCD-chunked swizzle kept (FETCH 69->17MB, r8).
#define MG_RELU 1
#define MG_ADDC 2
#define MG_BIAS 4
// remap: 0 plain fp32, 1 embed scatter fp32, 2 qkv -> bf16 QB/KB/VB (vector)
__global__ __launch_bounds__(512)
void gemm_mfma(const unsigned short* __restrict__ A,
               const unsigned short* __restrict__ B,
               const float* __restrict__ bias, float* __restrict__ C,
               unsigned short* __restrict__ qkv, unsigned short* __restrict__ vbuf,
               int M, int N, int K, int flags, int remap) {
  __shared__ short8 smem[3072];  // 48 KB: 2 x (A 8KB + B 16KB)
  const int tid = threadIdx.x;
  const int lane = tid & 63, wave = tid >> 6;     // wave 0..7
  const int wm = wave >> 2, wn = wave & 3;        // 2 x 4 wave grid
  const int nwg = gridDim.x * gridDim.y;
  const int orig = blockIdx.y * gridDim.x + blockIdx.x;
  const int swz = ((nwg & 7) == 0) ? (orig & 7) * (nwg >> 3) + (orig >> 3) : orig;
  const int m0 = (swz / gridDim.x) * 128, n0 = (swz % gridDim.x) * 256;
  const int r16 = lane & 15, quad = lane >> 4;
  const unsigned short* pa  = A + (long long)(m0 + 16 * wave + r16) * K + quad * 8;
  const unsigned short* pb0 = B + (long long)(n0 + 32 * wave + r16) * K + quad * 8;
  const unsigned short* pb1 = B + (long long)(n0 + 32 * wave + 16 + r16) * K + quad * 8;
  auto stage = [&](int bsel) {
    short8* Als = smem + bsel * 1536;        // [8][64] (8KB)
    short8* Bls = smem + bsel * 1536 + 512;  // [16][64] (16KB)
    gl2lds16(pa, Als + wave * 64);
    gl2lds16(pb0, Bls + (2 * wave) * 64);
    gl2lds16(pb1, Bls + (2 * wave + 1) * 64);
    pa += 32; pb0 += 32; pb1 += 32;
  };
  f32x4 acc[4][4] = {};
  stage(0);
  __syncthreads();  // buf0 ready
  int cur = 0;
  for (int k0 = 0; k0 < K; k0 += 32) {
    if (k0 + 32 < K) stage(cur ^ 1);  // issue next-step loads FIRST
    short8* Als = smem + cur * 1536;
    short8* Bls = smem + cur * 1536 + 512;
    short8 af[4], bfr[4];
#pragma unroll
    for (int mt = 0; mt < 4; mt++) af[mt] = Als[(wm * 4 + mt) * 64 + lane];
#pragma unroll
    for (int nt = 0; nt < 4; nt++) bfr[nt] = Bls[(wn * 4 + nt) * 64 + lane];
#pragma unroll
    for (int mt = 0; mt < 4; mt++)
#pragma unroll
      for (int nt = 0; nt < 4; nt++)
        acc[mt][nt] = __builtin_amdgcn_mfma_f32_16x16x32_bf16(
            af[mt], bfr[nt], acc[mt][nt], 0, 0, 0);
    __syncthreads();  // drains next-step loads; protects buf reuse
    cur ^= 1;
  }
  if (remap == 2) {
    // Ep aliases the staging memory (safe: last __syncthreads drained reads)
    unsigned short (*Ep)[32][64] = (unsigned short (*)[32][64])smem;  // 8x4KB
    int gn_base = n0 + wn * 64;
    int s = gn_base >> 9, hh = (gn_base >> 6) & 7;
    float scale = (s == 0) ? 0.125f : 1.f;
    unsigned short* basep =
        (s == 0) ? qkv : (s == 1) ? qkv + (long long)BHN * NF * DH : vbuf;
#pragma unroll
    for (int half = 0; half < 2; half++) {
      lds_fence();  // prior half's Ep reads drained (wave-local region)
#pragma unroll
      for (int mt = half * 2; mt < half * 2 + 2; mt++)
#pragma unroll
        for (int nt = 0; nt < 4; nt++)
#pragma unroll
          for (int r = 0; r < 4; r++)
            Ep[wave][(mt & 1) * 16 + quad * 4 + r][nt * 16 + r16] =
                f2bf(acc[mt][nt][r] * scale);
      lds_fence();
#pragma unroll
      for (int it = 0; it < 4; it++) {
        int idx = it * 64 + lane;
        int m_l = idx >> 3, sg = idx & 7;
        int gm = m0 + wm * 64 + half * 32 + m_l;
        int b = gm >> 13, n = gm & (NF - 1);
        int bh = b * HEADS + hh;
        short8 v = *(short8*)&Ep[wave][m_l][sg * 8];
        *(short8*)&basep[((long long)bh * NF + n) * DH + sg * 8] = v;
      }
    }
  } else {
#pragma unroll
    for (int mt = 0; mt < 4; mt++) {
#pragma unroll
      for (int nt = 0; nt < 4; nt++) {
#pragma unroll
        for (int r = 0; r < 4; r++) {
          int gm = m0 + wm * 64 + mt * 16 + quad * 4 + r;
          int gn = n0 + wn * 64 + nt * 16 + r16;
          if (gm >= M) continue;
          float v = acc[mt][nt][r];
          if (flags & MG_BIAS) v += bias[gn];
          long long idx;
          if (remap == 1) {
            int b = gm / 8191;
            int n = gm - b * 8191;
            idx = ((long long)(b * NF + 1 + n)) * DIM + gn;
          } else {
            idx = (long long)gm * N + gn;
          }
          if (flags & MG_ADDC) v += C[idx];
          if (flags & MG_RELU) v = fmaxf(v, 0.f);
          C[idx] = v;
        }
      }
    }
  }
}

// ---------------- fused attn1: LDS-resident K_landmark + Wm ---------------
// K (256x64, 32KB) and Wm (64x256, 32KB) staged ONCE per block via
// global_load_lds with XOR swizzle (LDS[row][c] = G[row][c^(row&7)], 16B
// units) -> all MFMA operands come from conflict-free LDS. 512 thr, 8
// waves x 2 row-tiles; 1 block/CU (98KB LDS). No-max softmax + ones-MFMA
// row sums.
__global__ __launch_bounds__(512)
void flash_attn1(const unsigned short* __restrict__ QB,
                 const unsigned short* __restrict__ KLB,
                 const unsigned short* __restrict__ WmB,
                 const unsigned short* __restrict__ XNC,
                 unsigned short* __restrict__ XNB2) {
  __shared__ unsigned short Klds[LM * DH];     // 32 KB
  __shared__ unsigned short Wlds[DH * LM];     // 32 KB
  __shared__ unsigned short Plds[8][16][136];  // 34 KB
  const int bh = blockIdx.y, b = bh >> 3, hh = bh & 7;
  const int tid = threadIdx.x, lane = tid & 63, wave = tid >> 6;
  const int r16 = lane & 15, quad = lane >> 4;
  const unsigned short* Aq = QB + (long long)bh * NF * DH;
  const unsigned short* Kg = KLB + (long long)bh * LM * DH;
  const unsigned short* Wg = WmB + (long long)bh * DH * LM;
#pragma unroll
  for (int j = 0; j < 4; j++) {  // K: 32 x 1KB units
    int u = j * 8 + wave;
    int s = u * 64 + lane;
    int row = s >> 3, ck = s & 7;
    gl2lds16(Kg + row * DH + ((ck ^ (row & 7)) << 3), (char*)Klds + u * 1024);
  }
#pragma unroll
  for (int j = 0; j < 4; j++) {  // Wm: 32 x 1KB units
    int u = j * 8 + wave;
    int s = u * 64 + lane;
    int row = s >> 5, ck = s & 31;
    gl2lds16(Wg + row * LM + ((ck ^ (row & 7)) << 3), (char*)Wlds + u * 1024);
  }
  __syncthreads();
  short8 ones;
#pragma unroll
  for (int j = 0; j < 8; j++) ((unsigned short*)&ones)[j] = 0x3F80;  // bf16 1.0
#pragma unroll
  for (int rt = 0; rt < 2; rt++) {
    const int m0w = blockIdx.x * 256 + (wave * 2 + rt) * 16;
    short8 af[2];
#pragma unroll
    for (int kc = 0; kc < 2; kc++)
      af[kc] = *(const short8*)&Aq[(long long)(m0w + r16) * DH + kc * 32 + quad * 8];
    f32x4 O[4] = {};
    f32x4 Ls = {};
#pragma unroll
    for (int t = 0; t < 2; t++) {
      int c0 = t * 128;
      f32x4 S[8] = {};
      __builtin_amdgcn_s_setprio(1);
#pragma unroll
      for (int nt = 0; nt < 8; nt++) {
        int kl = c0 + nt * 16 + r16;
#pragma unroll
        for (int kc = 0; kc < 2; kc++) {
          short8 bb = *(const short8*)((const char*)Klds + kl * 128 +
                                       (((kc * 4 + quad) ^ (kl & 7)) << 4));
          S[nt] = __builtin_amdgcn_mfma_f32_16x16x32_bf16(af[kc], bb, S[nt], 0, 0, 0);
        }
      }
      __builtin_amdgcn_s_setprio(0);
#pragma unroll
      for (int nt = 0; nt < 8; nt++)
#pragma unroll
        for (int r = 0; r < 4; r++)
          Plds[wave][quad * 4 + r][nt * 16 + r16] = f2bf(__expf(S[nt][r]));
      lds_fence();
      __builtin_amdgcn_s_setprio(1);
#pragma unroll
      for (int kc = 0; kc < 4; kc++) {
        short8 a = *(short8*)&Plds[wave][r16][kc * 32 + quad * 8];
        Ls = __builtin_amdgcn_mfma_f32_16x16x32_bf16(a, ones, Ls, 0, 0, 0);
#pragma unroll
        for (int nt2 = 0; nt2 < 4; nt2++) {
          int wrow = nt2 * 16 + r16;
          int cu = (c0 >> 3) + kc * 4 + quad;
          short8 bb = *(const short8*)((const char*)Wlds + wrow * 512 +
                                       ((cu ^ (wrow & 7)) << 4));
          O[nt2] = __builtin_amdgcn_mfma_f32_16x16x32_bf16(a, bb, O[nt2], 0, 0, 0);
        }
      }
      __builtin_amdgcn_s_setprio(0);
    }
    float invl[4];
#pragma unroll
    for (int r = 0; r < 4; r++) invl[r] = 1.f / Ls[r];
#pragma unroll
    for (int nt2 = 0; nt2 < 4; nt2++)
#pragma unroll
      for (int r = 0; r < 4; r++) {
        int row = m0w + quad * 4 + r;
        int d = nt2 * 16 + r16;
        long long gi = ((long long)(b * NF + row)) * DIM + hh * DH + d;
        XNB2[gi] = f2bf(O[nt2][r] * invl[r] + bf2f(XNC[gi]));
      }
  }
}

// ---------------- fused attn3: LDS-resident K/V chunk pipeline ------------
// Block = (ks, bh): all 256 landmark rows vs a 512-col KV chunk, processed
// as 4 sub-chunks of 128 with double-buffered K(16KB)+V(16KB) staging
// (m97 pattern). No-max + ones-MFMA math.
__device__ __forceinline__ void stage_kv3(const unsigned short* Kg,
                                          const unsigned short* Vg,
                                          unsigned short* Kb, unsigned short* Vb,
                                          int kv0, int wave, int lane) {
#pragma unroll
  for (int j = 0; j < 2; j++) {
    int u = j * 8 + wave;
    int s = u * 64 + lane;
    int kr = s >> 3, kc = s & 7;
    gl2lds16(Kg + (long long)(kv0 + kr) * DH + ((kc ^ (kr & 7)) << 3),
             (char*)Kb + u * 1024);
    int vr = s >> 4, vc = s & 15;
    gl2lds16(Vg + (long long)vr * NF + kv0 + ((vc ^ (vr & 7)) << 3),
             (char*)Vb + u * 1024);
  }
}

__global__ __launch_bounds__(512)
void flash_attn3(const unsigned short* __restrict__ QLB,
                 const unsigned short* __restrict__ KB,
                 const unsigned short* __restrict__ VT,
                 float* __restrict__ Opart, float* __restrict__ Lpart) {
  __shared__ unsigned short Klds[2][128 * DH];  // 2 x 16 KB
  __shared__ unsigned short Vlds[2][DH * 128];  // 2 x 16 KB
  __shared__ unsigned short Plds[8][16][136];   // 34 KB
  const int ks = blockIdx.x, bh = blockIdx.y;
  const int tid = threadIdx.x, lane = tid & 63, wave = tid >> 6;
  const int r16 = lane & 15, quad = lane >> 4;
  const unsigned short* Aq = QLB + (long long)bh * LM * DH;
  const unsigned short* Kg = KB + (long long)bh * NF * DH;
  const unsigned short* Vg = VT + (long long)bh * DH * NF;
  short8 af2[2][2];
#pragma unroll
  for (int rt = 0; rt < 2; rt++) {
    int m0w = (wave * 2 + rt) * 16;
#pragma unroll
    for (int kc = 0; kc < 2; kc++)
      af2[rt][kc] =
          *(const short8*)&Aq[(long long)(m0w + r16) * DH + kc * 32 + quad * 8];
  }
  short8 ones;
#pragma unroll
  for (int j = 0; j < 8; j++) ((unsigned short*)&ones)[j] = 0x3F80;  // bf16 1.0
  f32x4 O2[2][4] = {};
  f32x4 Ls2[2] = {};
  stage_kv3(Kg, Vg, Klds[0], Vlds[0], ks * 512, wave, lane);
  __syncthreads();
  for (int t = 0; t < 4; t++) {
    int cb = t & 1;
    if (t < 3)
      stage_kv3(Kg, Vg, Klds[cb ^ 1], Vlds[cb ^ 1], ks * 512 + (t + 1) * 128,
                wave, lane);
    const unsigned short* Kb = Klds[cb];
    const unsigned short* Vb = Vlds[cb];
#pragma unroll
    for (int rt = 0; rt < 2; rt++) {
      f32x4 S[8] = {};
      __builtin_amdgcn_s_setprio(1);
#pragma unroll
      for (int nt = 0; nt < 8; nt++) {
        int kl = nt * 16 + r16;
#pragma unroll
        for (int kc = 0; kc < 2; kc++) {
          short8 bb = *(const short8*)((const char*)Kb + kl * 128 +
                                       (((kc * 4 + quad) ^ (kl & 7)) << 4));
          S[nt] = __builtin_amdgcn_mfma_f32_16x16x32_bf16(af2[rt][kc], bb, S[nt],
                                                          0, 0, 0);
        }
      }
      __builtin_amdgcn_s_setprio(0);
#pragma unroll
      for (int nt = 0; nt < 8; nt++)
#pragma unroll
        for (int r = 0; r < 4; r++)
          Plds[wave][quad * 4 + r][nt * 16 + r16] = f2bf(__expf(S[nt][r]));
      lds_fence();
      __builtin_amdgcn_s_setprio(1);
#pragma unroll
      for (int kc2 = 0; kc2 < 4; kc2++) {
        short8 a = *(short8*)&Plds[wave][r16][kc2 * 32 + quad * 8];
        Ls2[rt] = __builtin_amdgcn_mfma_f32_16x16x32_bf16(a, ones, Ls2[rt], 0, 0, 0);
#pragma unroll
        for (int nt2 = 0; nt2 < 4; nt2++) {
          int vr = nt2 * 16 + r16;
          int u = kc2 * 4 + quad;
          short8 bb = *(const short8*)((const char*)Vb + vr * 256 +
                                       ((u ^ (vr & 7)) << 4));
          O2[rt][nt2] = __builtin_amdgcn_mfma_f32_16x16x32_bf16(a, bb, O2[rt][nt2],
                                                                0, 0, 0);
        }
      }
      __builtin_amdgcn_s_setprio(0);
    }
    __syncthreads();
  }
  float* Ob = Opart + (((long long)ks * BHN + bh) * LM) * DH;
#pragma unroll
  for (int rt = 0; rt < 2; rt++) {
    int m0w = (wave * 2 + rt) * 16;
#pragma unroll
    for (int nt2 = 0; nt2 < 4; nt2++)
#pragma unroll
      for (int r = 0; r < 4; r++)
        Ob[(long long)(m0w + quad * 4 + r) * DH + nt2 * 16 + r16] = O2[rt][nt2][r];
    if (r16 == 0)
#pragma unroll
      for (int r = 0; r < 4; r++)
        Lpart[((long long)ks * BHN + bh) * LM + m0w + quad * 4 + r] = Ls2[rt][r];
  }
}

__global__ __launch_bounds__(256)
void attn3_merge(const float* __restrict__ Opart, const float* __restrict__ Lpart,
                 float* __restrict__ O3) {
  int idx = blockIdx.x * 256 + threadIdx.x;  // 262144
  int bh = idx >> 14, rem = idx & 16383;
  int row = rem >> 6, d = rem & 63;
  float L = 0.f, acc = 0.f;
#pragma unroll
  for (int c = 0; c < 16; c++) {
    L += Lpart[((long long)c * BHN + bh) * LM + row];
    acc += Opart[(((long long)c * BHN + bh) * LM + row) * DH + d];
  }
  O3[((long long)bh * LM + row) * DH + d] = acc / L;
}

// ---------------- z0 = attn2^T / rowmax; writes bf16 normal + transposed ---
__global__ __launch_bounds__(256)
void zinit(const float* __restrict__ a2, const unsigned* __restrict__ red,
           unsigned short* __restrict__ zn, unsigned short* __restrict__ zt) {
  // softmax rows sum to 1 exactly => ref's "col" factor == 1; scale = 1/colmax
  float scale = 1.0f / __uint_as_float(red[1]);
  long long idx = (long long)blockIdx.x * 256 + threadIdx.x;
  int bh = (int)(idx >> 16);
  int ij = (int)(idx & 65535);
  int i = ij >> 8, j = ij & 255;
  zn[idx] = f2bf(a2[((long long)bh << 16) + (j << 8) + i] * scale);
  zt[idx] = f2bf(a2[idx] * scale);
}

// ---------------- pinv bf16 GEMM, full-K staging, dual-layout output -------
// C = alpha * (ident * A[m][n] + beta * (A@B)[m][n]); B given TRANSPOSED.
// 32x32 tiles (grid 8x8x16 = 1024 blocks, 4 blocks/CU) for latency overlap.
#define PV_CN 1   // write Cn bf16 [m][n]
#define PV_CT 2   // write Ct bf16 [n][m]
#define PV_CF 4   // write Cf fp32 [m][n]
#define PV_ID 8   // include ident*A[m][n] term (A@I = A)
__global__ __launch_bounds__(256)
void pinv_bf(const unsigned short* __restrict__ An,
             const unsigned short* __restrict__ Bt,
             unsigned short* __restrict__ Cn, unsigned short* __restrict__ Ct,
             float* __restrict__ Cf, float alpha, float ident, float beta,
             int flags) {
  __shared__ unsigned short Als[32][256];  // 16 KB, XOR-swizzled chunks
  __shared__ unsigned short Bls[32][256];
  const int batch = blockIdx.z;
  An += (long long)batch * 65536;
  Bt += (long long)batch * 65536;
  const int tid = threadIdx.x, lane = tid & 63, wave = tid >> 6;
  const int wm2 = wave >> 1, wn2 = wave & 1;
  const int m0 = blockIdx.y * 32, n0 = blockIdx.x * 32;
  const int r16 = lane & 15, quad = lane >> 4;
  // one-shot full-K staging. LDS physical chunk g holds logical k-chunk
  // (g&31)^(row&7) of row g>>5 (pre-swizzled global source, linear LDS dest).
#pragma unroll
  for (int j = 0; j < 4; j++) {
    int g = (j * 4 + wave) * 64 + lane;  // 0..1023
    int row = g >> 5, plog = (g & 31) ^ (row & 7);
    gl2lds16(An + ((m0 + row) << 8) + plog * 8,
             (char*)Als + (j * 4 + wave) * 1024);
    gl2lds16(Bt + ((n0 + row) << 8) + plog * 8,
             (char*)Bls + (j * 4 + wave) * 1024);
  }
  __syncthreads();
  f32x4 acc = {};
  const int arow = wm2 * 16 + r16, brow = wn2 * 16 + r16;
#pragma unroll
  for (int kk = 0; kk < 8; kk++) {
    short8 af = *(const short8*)((const char*)Als + arow * 512 +
                                 ((kk * 4 + quad) ^ (arow & 7)) * 16);
    short8 bfr = *(const short8*)((const char*)Bls + brow * 512 +
                                  ((kk * 4 + quad) ^ (brow & 7)) * 16);
    acc = __builtin_amdgcn_mfma_f32_16x16x32_bf16(af, bfr, acc, 0, 0, 0);
  }
  long long cb = (long long)batch * 65536;
  int ncol = n0 + wn2 * 16 + r16;
  float vals[4];
#pragma unroll
  for (int r = 0; r < 4; r++) {
    int mrow = wm2 * 16 + quad * 4 + r;  // local row in [0,32)
    float v = beta * acc[r];
    if (flags & PV_ID) {
      // A[m][n] read back from the staged (swizzled) A tile
      unsigned short a = *(const unsigned short*)(
          (const char*)Als + mrow * 512 +
          (((ncol >> 3) ^ (mrow & 7)) * 16) + (ncol & 7) * 2);
      v += ident * bf2f(a);
    }
    vals[r] = v * alpha;
    int gm = m0 + mrow;
    if (flags & PV_CN) Cn[cb + ((long long)gm << 8) + ncol] = f2bf(vals[r]);
    if (flags & PV_CF) Cf[cb + ((long long)gm << 8) + ncol] = vals[r];
  }
  if (flags & PV_CT) {
    ushort4 o;
    o.x = f2bf(vals[0]); o.y = f2bf(vals[1]);
    o.z = f2bf(vals[2]); o.w = f2bf(vals[3]);
    *(ushort4*)&Ct[cb + ((long long)ncol << 8) + m0 + wm2 * 16 + quad * 4] = o;
  }
}

// ---------------- batched GEMM (fp32: last pinv iter) ----------------
#define BG_BIDENT 16
__global__ __launch_bounds__(256)
void bgemm(const float* __restrict__ A, const float* __restrict__ B,
           float* __restrict__ C, int M, int N, int K,
           long long sA, long long sB, long long sC,
           float alpha, float ident, int flags) {
  const int batch = blockIdx.z;
  A += (long long)batch * sA;
  B += (long long)batch * sB;
  float* Cb = C + (long long)batch * sC;
  __shared__ float As[16][68];
  __shared__ float Bs[16][68];
  const int tid = threadIdx.x;
  const int tx = tid & 15, ty = tid >> 4;
  const int m0 = blockIdx.y * 64, n0 = blockIdx.x * 64;
  float acc[4][4] = {};
  for (int k0 = 0; k0 < K; k0 += 16) {
    {
      int k = tid & 15;
      int mBase = tid >> 4;
#pragma unroll
      for (int i = 0; i < 4; i++) {
        int m = mBase + i * 16;
        int gm = m0 + m;
        As[k][m] = (gm < M) ? A[(long long)gm * K + (k0 + k)] : 0.f;
      }
    }
    {
      int n = tid & 63;
      int kBase = tid >> 6;
#pragma unroll
      for (int i = 0; i < 4; i++) {
        int k = kBase + i * 4;
        int gn = n0 + n;
        float vb = (gn < N) ? B[(long long)(k0 + k) * N + gn] : 0.f;
        if (flags & BG_BIDENT) vb = ident * ((k0 + k) == gn ? 1.f : 0.f) - vb;
        Bs[k][n] = vb;
      }
    }
    __syncthreads();
#pragma unroll
    for (int k = 0; k < 16; k++) {
      float a[4], b[4];
#pragma unroll
      for (int i = 0; i < 4; i++) a[i] = As[k][ty * 4 + i];
#pragma unroll
      for (int j = 0; j < 4; j++) b[j] = Bs[k][tx * 4 + j];
#pragma unroll
      for (int i = 0; i < 4; i++)
#pragma unroll
        for (int j = 0; j < 4; j++) acc[i][j] = fmaf(a[i], b[j], acc[i][j]);
    }
    __syncthreads();
  }
#pragma unroll
  for (int i = 0; i < 4; i++) {
    int gm = m0 + ty * 4 + i;
    if (gm >= M) continue;
#pragma unroll
    for (int j = 0; j < 4; j++) {
      int gn = n0 + tx * 4 + j;
      if (gn >= N) continue;
      Cb[(long long)gm * N + gn] = alpha * acc[i][j];
    }
  }
}

// ---------------- Wm = z @ O3, written transposed bf16 WmT[bh][d][k] -------
__global__ __launch_bounds__(256)
void wm_gemm(const float* __restrict__ Z, const float* __restrict__ O3,
             unsigned short* __restrict__ WmT) {
  const int batch = blockIdx.y;
  const int m0 = blockIdx.x * 64;
  const float* A = Z + (long long)batch * 65536;
  const float* B = O3 + (long long)batch * LM * DH;
  __shared__ float As[16][68];
  __shared__ float Bs[16][68];
  const int tid = threadIdx.x, tx = tid & 15, ty = tid >> 4;
  float acc[4][4] = {};
  for (int k0 = 0; k0 < 256; k0 += 16) {
    {
      int k = tid & 15, mB = tid >> 4;
#pragma unroll
      for (int i = 0; i < 4; i++) {
        int m = mB + i * 16;
        As[k][m] = A[(long long)(m0 + m) * 256 + k0 + k];
      }
    }
    {
      int n = tid & 63, kB = tid >> 6;
#pragma unroll
      for (int i = 0; i < 4; i++) {
        int k = kB + i * 4;
        Bs[k][n] = B[(long long)(k0 + k) * DH + n];
      }
    }
    __syncthreads();
#pragma unroll
    for (int k = 0; k < 16; k++) {
      float a[4], b[4];
#pragma unroll
      for (int i = 0; i < 4; i++) a[i] = As[k][ty * 4 + i];
#pragma unroll
      for (int j = 0; j < 4; j++) b[j] = Bs[k][tx * 4 + j];
#pragma unroll
      for (int i = 0; i < 4; i++)
#pragma unroll
        for (int j = 0; j < 4; j++) acc[i][j] = fmaf(a[i], b[j], acc[i][j]);
    }
    __syncthreads();
  }
#pragma unroll
  for (int i = 0; i < 4; i++)
#pragma unroll
    for (int j = 0; j < 4; j++)
      WmT[((long long)batch * DH + tx * 4 + j) * LM + m0 + ty * 4 + i] =
          f2bf(acc[i][j]);
}

// ---------------- row layernorm over 512 -> bf16 ----------------
__global__ __launch_bounds__(256)
void layernorm_rows_bf16(const float* __restrict__ X, const float* __restrict__ g,
                         const float* __restrict__ bt,
                         unsigned short* __restrict__ Y) {
  __shared__ float sm[4];
  long long r = blockIdx.x;
  const float* x = X + r * DIM;
  int t = threadIdx.x;
  float v0 = x[t], v1 = x[t + 256];
  float mu = blockReduceSum256(v0 + v1, sm) * (1.f / DIM);
  float d0 = v0 - mu, d1 = v1 - mu;
  float var = blockReduceSum256(d0 * d0 + d1 * d1, sm) * (1.f / DIM);
  float rs = 1.0f / sqrtf(var + 1e-5f);
  unsigned short* y = Y + r * DIM;
  y[t] = f2bf(d0 * rs * g[t] + bt[t]);
  y[t + 256] = f2bf(d1 * rs * g[t + 256] + bt[t + 256]);
}

// ---------------- landmark means from bf16 q,k ----------------
__global__ __launch_bounds__(64)
void landmarks_k(const unsigned short* __restrict__ q,
                 const unsigned short* __restrict__ k,
                 float* __restrict__ ql, float* __restrict__ kl,
                 unsigned short* __restrict__ qlb,
                 unsigned short* __restrict__ klb) {
  int bh = blockIdx.x >> 8, i = blockIdx.x & 255, d = threadIdx.x;
  long long base = ((long long)bh * NF + i * 32) * DH + d;
  float sq = 0.f, sk = 0.f;
#pragma unroll 4
  for (int l = 0; l < 32; l++) {
    sq += bf2f(q[base + (long long)l * DH]);
    sk += bf2f(k[base + (long long)l * DH]);
  }
  long long o = ((long long)bh * LM + i) * DH + d;
  float mq = sq * (1.f / 32.f), mk = sk * (1.f / 32.f);
  ql[o] = mq; kl[o] = mk;
  qlb[o] = f2bf(mq); klb[o] = f2bf(mk);
}

// ---------------- sim2 + row softmax -> attn2 (fp32 + bf16) ----------------
__global__ __launch_bounds__(256)
void sim2_softmax(const float* __restrict__ ql, const float* __restrict__ kl,
                  float* __restrict__ a2, unsigned short* __restrict__ a2b) {
  __shared__ float qs[64];
  __shared__ float sm[4];
  int bh = blockIdx.x >> 8, i = blockIdx.x & 255, t = threadIdx.x;
  if (t < 64) qs[t] = ql[((long long)bh * LM + i) * DH + t];
  __syncthreads();
  const float* krow = kl + (long long)bh * LM * DH + (long long)t * DH;
  float s = 0.f;
#pragma unroll
  for (int d = 0; d < 64; d++) s += qs[d] * krow[d];
  float m = blockReduceMax256(s, sm);
  float e = expf(s - m);
  float sum = blockReduceSum256(e, sm);
  long long off = ((long long)bh * LM + i) * LM + t;
  float v = e / sum;
  a2[off] = v;
  a2b[off] = f2bf(v);
}

// ---------------- pinv global scale reduction (col sums only) --------------
// softmax rows sum to exactly 1 -> the ref's row-sum max factor == 1.
__global__ __launch_bounds__(256)
void pinv_reduce(const float* __restrict__ a2, unsigned* __restrict__ red) {
  __shared__ float sm[4];
  int bh = blockIdx.x, t = threadIdx.x;
  const float* A = a2 + (long long)bh * LM * LM;
  float cs = 0.f;
  for (int i = 0; i < 256; i++) cs += fabsf(A[i * 256 + t]);
  float cm = blockReduceMax256(cs, sm);
  if (t == 0) atomicMax(&red[1], __float_as_uint(cm));
}

// ---------------- depthwise conv residual -> bf16 scattered ----------------
__global__ __launch_bounds__(256)
void conv_res_bf16(const unsigned short* __restrict__ vt,
                   const float* __restrict__ cw,
                   unsigned short* __restrict__ out) {
  int bh = blockIdx.x >> 6, tile = blockIdx.x & 63;
  int b = bh >> 3, hh = bh & 7;
  int t = threadIdx.x;
  int d = t & 63, pg = t >> 6;
  float wr[33];
#pragma unroll
  for (int kk = 0; kk < 33; kk++) wr[kk] = cw[hh * 33 + kk];
  const unsigned short* src = &vt[((long long)bh * DH + d) * NF];
  int base = tile * 128 + pg * 32;
  int n0 = base - 16;
  float win[64];
#pragma unroll
  for (int jj = 0; jj < 8; jj++) {
    int c = n0 + jj * 8;
    if (c >= 0 && c + 7 < NF) {
      short8 v = *(const short8*)&src[c];
#pragma unroll
      for (int j = 0; j < 8; j++)
        win[jj * 8 + j] = bf2f((unsigned short)v[j]);
    } else {
#pragma unroll
      for (int j = 0; j < 8; j++) {
        int nn = c + j;
        win[jj * 8 + j] = (nn >= 0 && nn < NF) ? bf2f(src[nn]) : 0.f;
      }
    }
  }
  unsigned short* dst = &out[((long long)(b * NF + base)) * DIM + hh * DH + d];
#pragma unroll
  for (int p = 0; p < 32; p++) {
    float s = 0.f;
#pragma unroll
    for (int kk = 0; kk < 33; kk++) s = fmaf(wr[kk], win[p + kk], s);
    dst[(long long)p * DIM] = f2bf(s);
  }
}

// ---------------- final LN(row0) @ w2 + b2 ----------------
__global__ __launch_bounds__(256)
void final_head(const float* __restrict__ X, const float* __restrict__ g,
                const float* __restrict__ bt, const float* __restrict__ w2,
                const float* __restrict__ b2, float* __restrict__ out) {
  __shared__ float sm[4];
  int b = blockIdx.x, t = threadIdx.x;
  const float* row = X + (long long)b * NF * DIM;
  float v0 = row[t], v1 = row[t + 256];
  float mu = blockReduceSum256(v0 + v1, sm) * (1.f / DIM);
  float d0 = v0 - mu, d1 = v1 - mu;
  float var = blockReduceSum256(d0 * d0 + d1 * d1, sm) * (1.f / DIM);
  float rs = 1.0f / sqrtf(var + 1e-5f);
  float y0 = d0 * rs * g[t] + bt[t];
  float y1 = d1 * rs * g[t + 256] + bt[t + 256];
  float l0 = y0 * w2[t * 2 + 0] + y1 * w2[(t + 256) * 2 + 0];
  float l1 = y0 * w2[t * 2 + 1] + y1 * w2[(t + 256) * 2 + 1];
  l0 = blockReduceSum256(l0, sm);
  l1 = blockReduceSum256(l1, sm);
  if (t == 0) {
    out[b * 2 + 0] = l0 + b2[0];
    out[b * 2 + 1] = l1 + b2[1];
  }
}

extern "C" void kernel_launch(void* const* d_in, const int* in_sizes, int n_in,
                              void* d_out, int out_size, void* d_ws,
                              size_t ws_size, hipStream_t stream) {
  const float* h      = (const float*)d_in[0];
  const float* w1     = (const float*)d_in[1];
  const float* b1     = (const float*)d_in[2];
  const float* cls    = (const float*)d_in[3];
  const float* ln_g   = (const float*)d_in[4];
  const float* ln_b   = (const float*)d_in[5];
  const float* w_qkv  = (const float*)d_in[6];
  const float* w_out  = (const float*)d_in[7];
  const float* b_out  = (const float*)d_in[8];
  const float* conv_w = (const float*)d_in[9];
  const float* fn_g   = (const float*)d_in[10];
  const float* fn_b   = (const float*)d_in[11];
  const float* w2     = (const float*)d_in[12];
  const float* b2     = (const float*)d_in[13];

  float* ws = (float*)d_ws;
  const long long XSZ = (long long)2 * NF * DIM;      // 8388608
  const long long QSZ = (long long)BHN * NF * DH;     // 8388608
  float* X  = ws;                                     // 8.4M f
  unsigned short* STAGE = (unsigned short*)(X + XSZ); // staging us region
  unsigned short* HB   = STAGE;                 // embed bf16
  unsigned short* XNB1 = STAGE;                 // LN out bf16
  unsigned short* XNB2 = STAGE;                 // attn out bf16 (XNB1 dead)
  unsigned short* VB   = STAGE + XSZ;           // V row-major temp
  unsigned short* XNC  = STAGE + XSZ;           // conv bf16 (VB dead)
  unsigned short* QB = STAGE + 2 * XSZ;
  unsigned short* KB = QB + QSZ;
  unsigned short* VT = KB + QSZ;                // d-major
  float* QL = (float*)(VT + QSZ);
  float* KL = QL + 262144;
  unsigned short* QLB = (unsigned short*)(KL + 262144);
  unsigned short* KLB = QLB + 262144;
  float* A2 = (float*)(KLB + 262144);           // fp32 attn2 (reduce + it5)
  float* ZA = A2 + 1048576;                     // final fp32 z (wm_gemm)
  float* ZB = ZA + 1048576;                     // z4 fp32 (it5 input)
  float* P  = ZB + 1048576;                     // it5 fp32 temps
  float* T1 = P + 1048576;
  float* T2 = T1 + 1048576;
  float* Mpart = T2 + 1048576;                  // 65536 f (unused slot)
  float* Lpart = Mpart + 65536;                 // 65536 f
  float* O3 = Lpart + 65536;                    // 262144 f
  unsigned short* WmB = (unsigned short*)(O3 + 262144);  // 262144 us
  unsigned* RED = (unsigned*)(WmB + 262144);    // [unused, colmax, pad, pad]
  unsigned short* WT = (unsigned short*)(RED + 4);
  unsigned short* W1T = WT;                     // 524288 us
  unsigned short* WQ0 = W1T + 524288;           // 786432
  unsigned short* WQ1 = WQ0 + 786432;           // 786432
  unsigned short* WO0 = WQ1 + 786432;           // 262144
  unsigned short* WO1 = WO0 + 262144;           // 262144

  // Aliases with disjoint liveness inside the VB/XNC slot (16.77 MB):
  //   VB (qkv->vt) -> A2B (sim2->pinv it4 S1) -> Opart (attn3->merge) -> XNC
  unsigned short* A2B = VB;                     // bf16 attn2 (pinv A-operand)
  float* Opart = (float*)VB;                    // 16*16*256*64 f = 16.77 MB
  // bf16 pinv buffers alias fp32 it5 temps (live only during it0..4):
  unsigned short* Zan = (unsigned short*)P;     // z even-iter (normal)
  unsigned short* Zat = Zan + 1048576;          // z even-iter (transposed)
  unsigned short* Zbn = (unsigned short*)ZB;    // z odd-iter
  unsigned short* Zbt = Zbn + 1048576;
  unsigned short* Pn  = (unsigned short*)T1;    // P = A2@z
  unsigned short* Pt  = Pn + 1048576;
  unsigned short* T1t = (unsigned short*)T2;    // bracket temps (B-operand only)
  unsigned short* T2t = T1t + 1048576;

  // ---- prologue: cls, h cast, all weight transposes, embed ----
  write_cls<<<4, 256, 0, stream>>>(cls, X);
  cvt_bf16<<<16382, 256, 0, stream>>>(h, HB, (long long)16382 * 1024);
  cvt_transpose<<<dim3(512 / 32, 1024 / 32), 256, 0, stream>>>(w1, W1T, 1024, 512);
  cvt_transpose<<<dim3(1536 / 32, 512 / 32), 256, 0, stream>>>(w_qkv, WQ0, 512, 1536);
  cvt_transpose<<<dim3(1536 / 32, 512 / 32), 256, 0, stream>>>(
      w_qkv + (long long)DIM * 1536, WQ1, 512, 1536);
  cvt_transpose<<<dim3(512 / 32, 512 / 32), 256, 0, stream>>>(w_out, WO0, 512, 512);
  cvt_transpose<<<dim3(512 / 32, 512 / 32), 256, 0, stream>>>(
      w_out + (long long)DIM * DIM, WO1, 512, 512);
  gemm_mfma<<<dim3(2, 128), 512, 0, stream>>>(HB, W1T, b1, X, nullptr, nullptr,
                                              16382, 512, 1024, MG_RELU | MG_BIAS, 1);

  for (int L = 0; L < 2; L++) {
    layernorm_rows_bf16<<<2 * NF, 256, 0, stream>>>(X, ln_g + L * DIM,
                                                    ln_b + L * DIM, XNB1);
    gemm_mfma<<<dim3(6, 128), 512, 0, stream>>>(XNB1, L ? WQ1 : WQ0, nullptr,
                                                nullptr, QB, VB, 16384, 1536,
                                                512, 0, 2);
    vt_transpose<<<BHN * 128, 256, 0, stream>>>(VB, VT);

    landmarks_k<<<BHN * LM, 64, 0, stream>>>(QB, KB, QL, KL, QLB, KLB);
    sim2_softmax<<<BHN * LM, 256, 0, stream>>>(QL, KL, A2, A2B);
    hipMemsetAsync(RED, 0, 16, stream);
    pinv_reduce<<<BHN, 256, 0, stream>>>(A2, RED);
    zinit<<<4096, 256, 0, stream>>>(A2, RED, Zan, Zat);
    for (int it = 0; it < 5; it++) {  // bf16 iterations (NS self-corrects)
      const unsigned short* zcn = (it & 1) ? Zbn : Zan;
      const unsigned short* zct = (it & 1) ? Zbt : Zat;
      unsigned short* znn = (it & 1) ? Zan : Zbn;
      unsigned short* znt = (it & 1) ? Zat : Zbt;
      // P = A2 @ z
      pinv_bf<<<dim3(8, 8, BHN), 256, 0, stream>>>(
          A2B, zct, Pn, Pt, nullptr, 1.f, 0.f, 1.f, PV_CN | PV_CT);
      // T1 = 7P - P@P
      pinv_bf<<<dim3(8, 8, BHN), 256, 0, stream>>>(
          Pn, Pt, nullptr, T1t, nullptr, 1.f, 7.f, -1.f, PV_CT | PV_ID);
      // T2 = 15P - P@T1
      pinv_bf<<<dim3(8, 8, BHN), 256, 0, stream>>>(
          Pn, T1t, nullptr, T2t, nullptr, 1.f, 15.f, -1.f, PV_CT | PV_ID);
      // zn = 0.25*(13z - z@T2); it==4 writes fp32 z4 for the fp32 iteration
      if (it < 4)
        pinv_bf<<<dim3(8, 8, BHN), 256, 0, stream>>>(
            zcn, T2t, znn, znt, nullptr, 0.25f, 13.f, -1.f,
            PV_CN | PV_CT | PV_ID);
      else
        pinv_bf<<<dim3(8, 8, BHN), 256, 0, stream>>>(
            zcn, T2t, nullptr, nullptr, ZB, 0.25f, 13.f, -1.f, PV_CF | PV_ID);
    }
    // final iteration fp32
    bgemm<<<dim3(4, 4, BHN), 256, 0, stream>>>(A2, ZB, P, 256, 256, 256,
                                               65536, 65536, 65536, 1.f, 0.f, 0);
    bgemm<<<dim3(4, 4, BHN), 256, 0, stream>>>(P, P, T1, 256, 256, 256,
                                               65536, 65536, 65536, 1.f, 7.f,
                                               BG_BIDENT);
    bgemm<<<dim3(4, 4, BHN), 256, 0, stream>>>(P, T1, T2, 256, 256, 256,
                                               65536, 65536, 65536, 1.f, 15.f,
                                               BG_BIDENT);
    bgemm<<<dim3(4, 4, BHN), 256, 0, stream>>>(ZB, T2, ZA, 256, 256, 256,
                                               65536, 65536, 65536, 0.25f,
                                               13.f, BG_BIDENT);
    // final z in ZA

    // ---- fused attn3: LDS-resident chunks; plain (O,L) partials -> O3 ----
    flash_attn3<<<dim3(16, BHN), 512, 0, stream>>>(QLB, KB, VT, Opart, Lpart);
    attn3_merge<<<1024, 256, 0, stream>>>(Opart, Lpart, O3);

    // WmT(bf16) = (z @ O3)^T
    wm_gemm<<<dim3(4, BHN), 256, 0, stream>>>(ZA, O3, WmB);

    // conv residual (bf16) into XNC (overwrites dead Opart)
    conv_res_bf16<<<BHN * 64, 256, 0, stream>>>(VT, conv_w + L * 264, XNC);

    // ---- fused attn1 (LDS-resident K+Wm): XNB2 = bf16(conv + attn1@Wm) ----
    flash_attn1<<<dim3(32, BHN), 512, 0, stream>>>(QB, KLB, WmB, XNC, XNB2);

    // ---- X += XNB2 @ w_out + b_out ----
    gemm_mfma<<<dim3(2, 128), 512, 0, stream>>>(XNB2, L ? WO1 : WO0,
                                                b_out + L * DIM, X, nullptr,
                                                nullptr, 16384, 512, 512,
                                                MG_ADDC | MG_BIAS, 0);
  }
  final_head<<<2, 256, 0, stream>>>(X, fn_g, fn_b, w2, b2, (float*)d_out);
}

// Round 12
// 1203.974 us; speedup vs baseline: 1.1000x; 1.0360x over previous
//
#include <hip/hip_runtime.h>
#include <hip/hip_bf16.h>

#define DIM 512
#define HEADS 8
#define DH 64
#define LM 256
#define NF 8192
#define BHN 16   // batch(2) * heads(8)

typedef __attribute__((ext_vector_type(8))) short short8;
typedef __attribute__((ext_vector_type(4))) float f32x4;

__device__ __forceinline__ float bf2f(unsigned short u) {
  return __uint_as_float((unsigned)u << 16);
}
__device__ __forceinline__ unsigned short f2bf(float x) {
  unsigned u = __float_as_uint(x);
  unsigned r = u + 0x7fffu + ((u >> 16) & 1u);
  return (unsigned short)(r >> 16);
}

// async global->LDS, 16B per lane; lds dest = wave-uniform base + lane*16
__device__ __forceinline__ void gl2lds16(const void* g, void* l) {
  __builtin_amdgcn_global_load_lds(
      (const __attribute__((address_space(1))) void*)g,
      (__attribute__((address_space(3))) void*)l, 16, 0, 0);
}

// LDS-only fence: wait ds ops, then block scheduler from hoisting MFMAs
// above the wait (rule: inline-asm lgkmcnt needs a following sched_barrier).
__device__ __forceinline__ void lds_fence() {
  asm volatile("s_waitcnt lgkmcnt(0)" ::: "memory");
  __builtin_amdgcn_sched_barrier(0);
}

// ---------------- reduction helpers ----------------
__device__ __forceinline__ float waveReduceSum(float v) {
#pragma unroll
  for (int o = 1; o < 64; o <<= 1) v += __shfl_xor(v, o);
  return v;
}
__device__ __forceinline__ float waveReduceMax(float v) {
#pragma unroll
  for (int o = 1; o < 64; o <<= 1) v = fmaxf(v, __shfl_xor(v, o));
  return v;
}
__device__ __forceinline__ float blockReduceSum256(float v, float* sm) {
  v = waveReduceSum(v);
  int w = threadIdx.x >> 6;
  __syncthreads();
  if ((threadIdx.x & 63) == 0) sm[w] = v;
  __syncthreads();
  return sm[0] + sm[1] + sm[2] + sm[3];
}
__device__ __forceinline__ float blockReduceMax256(float v, float* sm) {
  v = waveReduceMax(v);
  int w = threadIdx.x >> 6;
  __syncthreads();
  if ((threadIdx.x & 63) == 0) sm[w] = v;
  __syncthreads();
  return fmaxf(fmaxf(sm[0], sm[1]), fmaxf(sm[2], sm[3]));
}

// ---------------- casts ----------------
__global__ __launch_bounds__(256)
void cvt_bf16(const float* __restrict__ in, unsigned short* __restrict__ out,
              long long n) {
  long long i = ((long long)blockIdx.x * 256 + threadIdx.x) * 4;
  if (i + 3 < n) {
    float4 v = *(const float4*)&in[i];
    ushort4 o;
    o.x = f2bf(v.x); o.y = f2bf(v.y); o.z = f2bf(v.z); o.w = f2bf(v.w);
    *(ushort4*)&out[i] = o;
  } else {
    for (; i < n; i++) out[i] = f2bf(in[i]);
  }
}

// transpose+cast: in fp32 [K][N] -> out bf16 [N][K]
__global__ __launch_bounds__(256)
void cvt_transpose(const float* __restrict__ in, unsigned short* __restrict__ out,
                   int Kd, int Nd) {
  __shared__ float t[32][33];
  int x = threadIdx.x & 31, y = threadIdx.x >> 5;
#pragma unroll
  for (int i = 0; i < 32; i += 8) {
    int k = blockIdx.y * 32 + y + i, n = blockIdx.x * 32 + x;
    t[y + i][x] = in[(long long)k * Nd + n];
  }
  __syncthreads();
#pragma unroll
  for (int i = 0; i < 32; i += 8) {
    int n = blockIdx.x * 32 + y + i, k = blockIdx.y * 32 + x;
    out[(long long)n * Kd + k] = f2bf(t[x][y + i]);
  }
}

// VB [bh][n][d] bf16 -> VT [bh][d][n] bf16
__global__ __launch_bounds__(256)
void vt_transpose(const unsigned short* __restrict__ VB,
                  unsigned short* __restrict__ VT) {
  __shared__ unsigned short t[64][80];
  int bh = blockIdx.x >> 7, tile = blockIdx.x & 127;
  int n0 = tile * 64;
  int tid = threadIdx.x;
#pragma unroll
  for (int it = 0; it < 2; it++) {
    int s = it * 256 + tid;
    int nl = s >> 3, sg = s & 7;
    *(short8*)&t[nl][sg * 8] =
        *(const short8*)&VB[((long long)bh * NF + n0 + nl) * DH + sg * 8];
  }
  __syncthreads();
#pragma unroll
  for (int it = 0; it < 2; it++) {
    int s = it * 256 + tid;
    int dl = s >> 3, sg = s & 7;
    short8 v;
#pragma unroll
    for (int j = 0; j < 8; j++) ((unsigned short*)&v)[j] = t[sg * 8 + j][dl];
    *(short8*)&VT[((long long)bh * DH + dl) * NF + n0 + sg * 8] = v;
  }
}

// ---------------- cls row write ----------------
__global__ __launch_bounds__(256) void write_cls(const float* __restrict__ cls,
                                                 float* __restrict__ X) {
  int t = blockIdx.x * 256 + threadIdx.x;
  int b = t >> 9, c = t & 511;
  X[(long long)b * NF * DIM + c] = cls[c];
}

// ---------------- bf16 MFMA GEMM (projections) ----------------------------
// r12: 128x256 tile, 8 waves, 2-buffer COUNTED-vmcnt pipeline: per step
// {stage(t+1); vmcnt(3); s_barrier; ds_read+MFMA; s_barrier} -- next tile's
// 3 loads stay in flight across the barrier (never drain to 0 in-loop).
// Targets the 1-block/CU dispatches (embed/wout) where the old syncthreads
// drain was fully exposed (r11: MfmaUtil 5%, occ 18%). PRE template adds
// C-prefetch (32 regs) for the ADDC epilogue without costing qkv occupancy.
#define MG_RELU 1
#define MG_ADDC 2
#define MG_BIAS 4
// remap: 0 plain fp32, 1 embed scatter fp32, 2 qkv -> bf16 QB/KB/VB (vector)
template <int PRE>
__global__ __launch_bounds__(512)
void gemm_mfma(const unsigned short* __restrict__ A,
               const unsigned short* __restrict__ B,
               const float* __restrict__ bias, float* __restrict__ C,
               unsigned short* __restrict__ qkv, unsigned short* __restrict__ vbuf,
               int M, int N, int K, int flags, int remap) {
  __shared__ short8 smem[3072];  // 48 KB: 2 x (A 8KB + B 16KB)
  const int tid = threadIdx.x;
  const int lane = tid & 63, wave = tid >> 6;     // wave 0..7
  const int wm = wave >> 2, wn = wave & 3;        // 2 x 4 wave grid
  const int nwg = gridDim.x * gridDim.y;
  const int orig = blockIdx.y * gridDim.x + blockIdx.x;
  const int swz = ((nwg & 7) == 0) ? (orig & 7) * (nwg >> 3) + (orig >> 3) : orig;
  const int m0 = (swz / gridDim.x) * 128, n0 = (swz % gridDim.x) * 256;
  const int r16 = lane & 15, quad = lane >> 4;
  const unsigned short* pa  = A + (long long)(m0 + 16 * wave + r16) * K + quad * 8;
  const unsigned short* pb0 = B + (long long)(n0 + 32 * wave + r16) * K + quad * 8;
  const unsigned short* pb1 = B + (long long)(n0 + 32 * wave + 16 + r16) * K + quad * 8;
  auto stage = [&](int bsel) {
    short8* Als = smem + bsel * 1536;        // [8][64] (8KB)
    short8* Bls = smem + bsel * 1536 + 512;  // [16][64] (16KB)
    gl2lds16(pa, Als + wave * 64);
    gl2lds16(pb0, Bls + (2 * wave) * 64);
    gl2lds16(pb1, Bls + (2 * wave + 1) * 64);
    pa += 32; pb0 += 32; pb1 += 32;
  };
  // C prefetch (ADDC only, remap==0): issue 32 of the 64 per-lane C reads
  // BEFORE the K-loop; they complete under the first tile wait. Bit-identical.
  float cpre[2][4][4];
  if (PRE && (flags & MG_ADDC)) {
#pragma unroll
    for (int mt = 0; mt < 2; mt++)
#pragma unroll
      for (int nt = 0; nt < 4; nt++)
#pragma unroll
        for (int r = 0; r < 4; r++) {
          int gm = m0 + wm * 64 + mt * 16 + quad * 4 + r;
          int gn = n0 + wn * 64 + nt * 16 + r16;
          cpre[mt][nt][r] = C[(long long)gm * N + gn];
        }
  }
  f32x4 acc[4][4] = {};
  const int nsteps = K >> 5;  // 16 or 32
  stage(0);
  for (int t = 0; t < nsteps; t++) {
    if (t + 1 < nsteps) {
      stage((t + 1) & 1);  // buf((t+1)&1): its readers finished at step t-1
      asm volatile("s_waitcnt vmcnt(3)" ::: "memory");  // tile t landed
    } else {
      asm volatile("s_waitcnt vmcnt(0)" ::: "memory");
    }
    __builtin_amdgcn_sched_barrier(0);
    __builtin_amdgcn_s_barrier();  // all waves: buf(t) fully written
    short8* Als = smem + (t & 1) * 1536;
    short8* Bls = smem + (t & 1) * 1536 + 512;
    short8 af[4], bfr[4];
#pragma unroll
    for (int mt = 0; mt < 4; mt++) af[mt] = Als[(wm * 4 + mt) * 64 + lane];
#pragma unroll
    for (int nt = 0; nt < 4; nt++) bfr[nt] = Bls[(wn * 4 + nt) * 64 + lane];
#pragma unroll
    for (int mt = 0; mt < 4; mt++)
#pragma unroll
      for (int nt = 0; nt < 4; nt++)
        acc[mt][nt] = __builtin_amdgcn_mfma_f32_16x16x32_bf16(
            af[mt], bfr[nt], acc[mt][nt], 0, 0, 0);
    __builtin_amdgcn_s_barrier();  // reads of buf(t) done before overwrite
  }
  if (remap == 2) {
    // Ep aliases the staging memory (safe: final vmcnt(0)+barrier drained all)
    unsigned short (*Ep)[32][64] = (unsigned short (*)[32][64])smem;  // 8x4KB
    int gn_base = n0 + wn * 64;
    int s = gn_base >> 9, hh = (gn_base >> 6) & 7;
    float scale = (s == 0) ? 0.125f : 1.f;
    unsigned short* basep =
        (s == 0) ? qkv : (s == 1) ? qkv + (long long)BHN * NF * DH : vbuf;
#pragma unroll
    for (int half = 0; half < 2; half++) {
      lds_fence();  // prior half's Ep reads drained (wave-local region)
#pragma unroll
      for (int mt = half * 2; mt < half * 2 + 2; mt++)
#pragma unroll
        for (int nt = 0; nt < 4; nt++)
#pragma unroll
          for (int r = 0; r < 4; r++)
            Ep[wave][(mt & 1) * 16 + quad * 4 + r][nt * 16 + r16] =
                f2bf(acc[mt][nt][r] * scale);
      lds_fence();
#pragma unroll
      for (int it = 0; it < 4; it++) {
        int idx = it * 64 + lane;
        int m_l = idx >> 3, sg = idx & 7;
        int gm = m0 + wm * 64 + half * 32 + m_l;
        int b = gm >> 13, n = gm & (NF - 1);
        int bh = b * HEADS + hh;
        short8 v = *(short8*)&Ep[wave][m_l][sg * 8];
        *(short8*)&basep[((long long)bh * NF + n) * DH + sg * 8] = v;
      }
    }
  } else {
#pragma unroll
    for (int mt = 0; mt < 4; mt++) {
#pragma unroll
      for (int nt = 0; nt < 4; nt++) {
#pragma unroll
        for (int r = 0; r < 4; r++) {
          int gm = m0 + wm * 64 + mt * 16 + quad * 4 + r;
          int gn = n0 + wn * 64 + nt * 16 + r16;
          if (gm >= M) continue;
          float v = acc[mt][nt][r];
          if (flags & MG_BIAS) v += bias[gn];
          long long idx;
          if (remap == 1) {
            int b = gm / 8191;
            int n = gm - b * 8191;
            idx = ((long long)(b * NF + 1 + n)) * DIM + gn;
          } else {
            idx = (long long)gm * N + gn;
          }
          if (flags & MG_ADDC) {
            if (PRE && mt < 2) v += cpre[mt][nt][r];
            else v += C[idx];
          }
          if (flags & MG_RELU) v = fmaxf(v, 0.f);
          C[idx] = v;
        }
      }
    }
  }
}

// ---------------- fused attn1: LDS-resident K_landmark + Wm ---------------
// K (256x64, 32KB) and Wm (64x256, 32KB) staged ONCE per block via
// global_load_lds with XOR swizzle (LDS[row][c] = G[row][c^(row&7)], 16B
// units) -> all MFMA operands come from conflict-free LDS. 512 thr, 8
// waves x 2 row-tiles; 1 block/CU (98KB LDS). No-max softmax + ones-MFMA
// row sums.
__global__ __launch_bounds__(512)
void flash_attn1(const unsigned short* __restrict__ QB,
                 const unsigned short* __restrict__ KLB,
                 const unsigned short* __restrict__ WmB,
                 const unsigned short* __restrict__ XNC,
                 unsigned short* __restrict__ XNB2) {
  __shared__ unsigned short Klds[LM * DH];     // 32 KB
  __shared__ unsigned short Wlds[DH * LM];     // 32 KB
  __shared__ unsigned short Plds[8][16][136];  // 34 KB
  const int bh = blockIdx.y, b = bh >> 3, hh = bh & 7;
  const int tid = threadIdx.x, lane = tid & 63, wave = tid >> 6;
  const int r16 = lane & 15, quad = lane >> 4;
  const unsigned short* Aq = QB + (long long)bh * NF * DH;
  const unsigned short* Kg = KLB + (long long)bh * LM * DH;
  const unsigned short* Wg = WmB + (long long)bh * DH * LM;
#pragma unroll
  for (int j = 0; j < 4; j++) {  // K: 32 x 1KB units
    int u = j * 8 + wave;
    int s = u * 64 + lane;
    int row = s >> 3, ck = s & 7;
    gl2lds16(Kg + row * DH + ((ck ^ (row & 7)) << 3), (char*)Klds + u * 1024);
  }
#pragma unroll
  for (int j = 0; j < 4; j++) {  // Wm: 32 x 1KB units
    int u = j * 8 + wave;
    int s = u * 64 + lane;
    int row = s >> 5, ck = s & 31;
    gl2lds16(Wg + row * LM + ((ck ^ (row & 7)) << 3), (char*)Wlds + u * 1024);
  }
  __syncthreads();
  short8 ones;
#pragma unroll
  for (int j = 0; j < 8; j++) ((unsigned short*)&ones)[j] = 0x3F80;  // bf16 1.0
#pragma unroll
  for (int rt = 0; rt < 2; rt++) {
    const int m0w = blockIdx.x * 256 + (wave * 2 + rt) * 16;
    short8 af[2];
#pragma unroll
    for (int kc = 0; kc < 2; kc++)
      af[kc] = *(const short8*)&Aq[(long long)(m0w + r16) * DH + kc * 32 + quad * 8];
    f32x4 O[4] = {};
    f32x4 Ls = {};
#pragma unroll
    for (int t = 0; t < 2; t++) {
      int c0 = t * 128;
      f32x4 S[8] = {};
      __builtin_amdgcn_s_setprio(1);
#pragma unroll
      for (int nt = 0; nt < 8; nt++) {
        int kl = c0 + nt * 16 + r16;
#pragma unroll
        for (int kc = 0; kc < 2; kc++) {
          short8 bb = *(const short8*)((const char*)Klds + kl * 128 +
                                       (((kc * 4 + quad) ^ (kl & 7)) << 4));
          S[nt] = __builtin_amdgcn_mfma_f32_16x16x32_bf16(af[kc], bb, S[nt], 0, 0, 0);
        }
      }
      __builtin_amdgcn_s_setprio(0);
#pragma unroll
      for (int nt = 0; nt < 8; nt++)
#pragma unroll
        for (int r = 0; r < 4; r++)
          Plds[wave][quad * 4 + r][nt * 16 + r16] = f2bf(__expf(S[nt][r]));
      lds_fence();
      __builtin_amdgcn_s_setprio(1);
#pragma unroll
      for (int kc = 0; kc < 4; kc++) {
        short8 a = *(short8*)&Plds[wave][r16][kc * 32 + quad * 8];
        Ls = __builtin_amdgcn_mfma_f32_16x16x32_bf16(a, ones, Ls, 0, 0, 0);
#pragma unroll
        for (int nt2 = 0; nt2 < 4; nt2++) {
          int wrow = nt2 * 16 + r16;
          int cu = (c0 >> 3) + kc * 4 + quad;
          short8 bb = *(const short8*)((const char*)Wlds + wrow * 512 +
                                       ((cu ^ (wrow & 7)) << 4));
          O[nt2] = __builtin_amdgcn_mfma_f32_16x16x32_bf16(a, bb, O[nt2], 0, 0, 0);
        }
      }
      __builtin_amdgcn_s_setprio(0);
    }
    float invl[4];
#pragma unroll
    for (int r = 0; r < 4; r++) invl[r] = 1.f / Ls[r];
#pragma unroll
    for (int nt2 = 0; nt2 < 4; nt2++)
#pragma unroll
      for (int r = 0; r < 4; r++) {
        int row = m0w + quad * 4 + r;
        int d = nt2 * 16 + r16;
        long long gi = ((long long)(b * NF + row)) * DIM + hh * DH + d;
        XNB2[gi] = f2bf(O[nt2][r] * invl[r] + bf2f(XNC[gi]));
      }
  }
}

// ---------------- fused attn3: LDS-resident K/V chunk pipeline ------------
// Block = (ks, bh): all 256 landmark rows vs a 512-col KV chunk, processed
// as 4 sub-chunks of 128 with double-buffered K(16KB)+V(16KB) staging
// (m97 pattern). No-max + ones-MFMA math.
__device__ __forceinline__ void stage_kv3(const unsigned short* Kg,
                                          const unsigned short* Vg,
                                          unsigned short* Kb, unsigned short* Vb,
                                          int kv0, int wave, int lane) {
#pragma unroll
  for (int j = 0; j < 2; j++) {
    int u = j * 8 + wave;
    int s = u * 64 + lane;
    int kr = s >> 3, kc = s & 7;
    gl2lds16(Kg + (long long)(kv0 + kr) * DH + ((kc ^ (kr & 7)) << 3),
             (char*)Kb + u * 1024);
    int vr = s >> 4, vc = s & 15;
    gl2lds16(Vg + (long long)vr * NF + kv0 + ((vc ^ (vr & 7)) << 3),
             (char*)Vb + u * 1024);
  }
}

__global__ __launch_bounds__(512)
void flash_attn3(const unsigned short* __restrict__ QLB,
                 const unsigned short* __restrict__ KB,
                 const unsigned short* __restrict__ VT,
                 float* __restrict__ Opart, float* __restrict__ Lpart) {
  __shared__ unsigned short Klds[2][128 * DH];  // 2 x 16 KB
  __shared__ unsigned short Vlds[2][DH * 128];  // 2 x 16 KB
  __shared__ unsigned short Plds[8][16][136];   // 34 KB
  const int ks = blockIdx.x, bh = blockIdx.y;
  const int tid = threadIdx.x, lane = tid & 63, wave = tid >> 6;
  const int r16 = lane & 15, quad = lane >> 4;
  const unsigned short* Aq = QLB + (long long)bh * LM * DH;
  const unsigned short* Kg = KB + (long long)bh * NF * DH;
  const unsigned short* Vg = VT + (long long)bh * DH * NF;
  short8 af2[2][2];
#pragma unroll
  for (int rt = 0; rt < 2; rt++) {
    int m0w = (wave * 2 + rt) * 16;
#pragma unroll
    for (int kc = 0; kc < 2; kc++)
      af2[rt][kc] =
          *(const short8*)&Aq[(long long)(m0w + r16) * DH + kc * 32 + quad * 8];
  }
  short8 ones;
#pragma unroll
  for (int j = 0; j < 8; j++) ((unsigned short*)&ones)[j] = 0x3F80;  // bf16 1.0
  f32x4 O2[2][4] = {};
  f32x4 Ls2[2] = {};
  stage_kv3(Kg, Vg, Klds[0], Vlds[0], ks * 512, wave, lane);
  __syncthreads();
  for (int t = 0; t < 4; t++) {
    int cb = t & 1;
    if (t < 3)
      stage_kv3(Kg, Vg, Klds[cb ^ 1], Vlds[cb ^ 1], ks * 512 + (t + 1) * 128,
                wave, lane);
    const unsigned short* Kb = Klds[cb];
    const unsigned short* Vb = Vlds[cb];
#pragma unroll
    for (int rt = 0; rt < 2; rt++) {
      f32x4 S[8] = {};
      __builtin_amdgcn_s_setprio(1);
#pragma unroll
      for (int nt = 0; nt < 8; nt++) {
        int kl = nt * 16 + r16;
#pragma unroll
        for (int kc = 0; kc < 2; kc++) {
          short8 bb = *(const short8*)((const char*)Kb + kl * 128 +
                                       (((kc * 4 + quad) ^ (kl & 7)) << 4));
          S[nt] = __builtin_amdgcn_mfma_f32_16x16x32_bf16(af2[rt][kc], bb, S[nt],
                                                          0, 0, 0);
        }
      }
      __builtin_amdgcn_s_setprio(0);
#pragma unroll
      for (int nt = 0; nt < 8; nt++)
#pragma unroll
        for (int r = 0; r < 4; r++)
          Plds[wave][quad * 4 + r][nt * 16 + r16] = f2bf(__expf(S[nt][r]));
      lds_fence();
      __builtin_amdgcn_s_setprio(1);
#pragma unroll
      for (int kc2 = 0; kc2 < 4; kc2++) {
        short8 a = *(short8*)&Plds[wave][r16][kc2 * 32 + quad * 8];
        Ls2[rt] = __builtin_amdgcn_mfma_f32_16x16x32_bf16(a, ones, Ls2[rt], 0, 0, 0);
#pragma unroll
        for (int nt2 = 0; nt2 < 4; nt2++) {
          int vr = nt2 * 16 + r16;
          int u = kc2 * 4 + quad;
          short8 bb = *(const short8*)((const char*)Vb + vr * 256 +
                                       ((u ^ (vr & 7)) << 4));
          O2[rt][nt2] = __builtin_amdgcn_mfma_f32_16x16x32_bf16(a, bb, O2[rt][nt2],
                                                                0, 0, 0);
        }
      }
      __builtin_amdgcn_s_setprio(0);
    }
    __syncthreads();
  }
  float* Ob = Opart + (((long long)ks * BHN + bh) * LM) * DH;
#pragma unroll
  for (int rt = 0; rt < 2; rt++) {
    int m0w = (wave * 2 + rt) * 16;
#pragma unroll
    for (int nt2 = 0; nt2 < 4; nt2++)
#pragma unroll
      for (int r = 0; r < 4; r++)
        Ob[(long long)(m0w + quad * 4 + r) * DH + nt2 * 16 + r16] = O2[rt][nt2][r];
    if (r16 == 0)
#pragma unroll
      for (int r = 0; r < 4; r++)
        Lpart[((long long)ks * BHN + bh) * LM + m0w + quad * 4 + r] = Ls2[rt][r];
  }
}

__global__ __launch_bounds__(256)
void attn3_merge(const float* __restrict__ Opart, const float* __restrict__ Lpart,
                 float* __restrict__ O3) {
  int idx = blockIdx.x * 256 + threadIdx.x;  // 262144
  int bh = idx >> 14, rem = idx & 16383;
  int row = rem >> 6, d = rem & 63;
  float L = 0.f, acc = 0.f;
#pragma unroll
  for (int c = 0; c < 16; c++) {
    L += Lpart[((long long)c * BHN + bh) * LM + row];
    acc += Opart[(((long long)c * BHN + bh) * LM + row) * DH + d];
  }
  O3[((long long)bh * LM + row) * DH + d] = acc / L;
}

// ---------------- z0 = attn2^T / rowmax; writes bf16 normal + transposed ---
__global__ __launch_bounds__(256)
void zinit(const float* __restrict__ a2, const unsigned* __restrict__ red,
           unsigned short* __restrict__ zn, unsigned short* __restrict__ zt) {
  // softmax rows sum to 1 exactly => ref's "col" factor == 1; scale = 1/colmax
  float scale = 1.0f / __uint_as_float(red[1]);
  long long idx = (long long)blockIdx.x * 256 + threadIdx.x;
  int bh = (int)(idx >> 16);
  int ij = (int)(idx & 65535);
  int i = ij >> 8, j = ij & 255;
  zn[idx] = f2bf(a2[((long long)bh << 16) + (j << 8) + i] * scale);
  zt[idx] = f2bf(a2[idx] * scale);
}

// ---------------- pinv bf16 GEMM, full-K staging, dual-layout output -------
// C = alpha * (ident * A[m][n] + beta * (A@B)[m][n]); B given TRANSPOSED.
// 32x32 tiles (grid 8x8x16 = 1024 blocks, 4 blocks/CU) for latency overlap.
#define PV_CN 1   // write Cn bf16 [m][n]
#define PV_CT 2   // write Ct bf16 [n][m]
#define PV_CF 4   // write Cf fp32 [m][n]
#define PV_ID 8   // include ident*A[m][n] term (A@I = A)
__global__ __launch_bounds__(256)
void pinv_bf(const unsigned short* __restrict__ An,
             const unsigned short* __restrict__ Bt,
             unsigned short* __restrict__ Cn, unsigned short* __restrict__ Ct,
             float* __restrict__ Cf, float alpha, float ident, float beta,
             int flags) {
  __shared__ unsigned short Als[32][256];  // 16 KB, XOR-swizzled chunks
  __shared__ unsigned short Bls[32][256];
  const int batch = blockIdx.z;
  An += (long long)batch * 65536;
  Bt += (long long)batch * 65536;
  const int tid = threadIdx.x, lane = tid & 63, wave = tid >> 6;
  const int wm2 = wave >> 1, wn2 = wave & 1;
  const int m0 = blockIdx.y * 32, n0 = blockIdx.x * 32;
  const int r16 = lane & 15, quad = lane >> 4;
  // one-shot full-K staging. LDS physical chunk g holds logical k-chunk
  // (g&31)^(row&7) of row g>>5 (pre-swizzled global source, linear LDS dest).
#pragma unroll
  for (int j = 0; j < 4; j++) {
    int g = (j * 4 + wave) * 64 + lane;  // 0..1023
    int row = g >> 5, plog = (g & 31) ^ (row & 7);
    gl2lds16(An + ((m0 + row) << 8) + plog * 8,
             (char*)Als + (j * 4 + wave) * 1024);
    gl2lds16(Bt + ((n0 + row) << 8) + plog * 8,
             (char*)Bls + (j * 4 + wave) * 1024);
  }
  __syncthreads();
  f32x4 acc = {};
  const int arow = wm2 * 16 + r16, brow = wn2 * 16 + r16;
#pragma unroll
  for (int kk = 0; kk < 8; kk++) {
    short8 af = *(const short8*)((const char*)Als + arow * 512 +
                                 ((kk * 4 + quad) ^ (arow & 7)) * 16);
    short8 bfr = *(const short8*)((const char*)Bls + brow * 512 +
                                  ((kk * 4 + quad) ^ (brow & 7)) * 16);
    acc = __builtin_amdgcn_mfma_f32_16x16x32_bf16(af, bfr, acc, 0, 0, 0);
  }
  long long cb = (long long)batch * 65536;
  int ncol = n0 + wn2 * 16 + r16;
  float vals[4];
#pragma unroll
  for (int r = 0; r < 4; r++) {
    int mrow = wm2 * 16 + quad * 4 + r;  // local row in [0,32)
    float v = beta * acc[r];
    if (flags & PV_ID) {
      // A[m][n] read back from the staged (swizzled) A tile
      unsigned short a = *(const unsigned short*)(
          (const char*)Als + mrow * 512 +
          (((ncol >> 3) ^ (mrow & 7)) * 16) + (ncol & 7) * 2);
      v += ident * bf2f(a);
    }
    vals[r] = v * alpha;
    int gm = m0 + mrow;
    if (flags & PV_CN) Cn[cb + ((long long)gm << 8) + ncol] = f2bf(vals[r]);
    if (flags & PV_CF) Cf[cb + ((long long)gm << 8) + ncol] = vals[r];
  }
  if (flags & PV_CT) {
    ushort4 o;
    o.x = f2bf(vals[0]); o.y = f2bf(vals[1]);
    o.z = f2bf(vals[2]); o.w = f2bf(vals[3]);
    *(ushort4*)&Ct[cb + ((long long)ncol << 8) + m0 + wm2 * 16 + quad * 4] = o;
  }
}

// ---------------- batched GEMM (fp32: last pinv iter) ----------------
#define BG_BIDENT 16
__global__ __launch_bounds__(256)
void bgemm(const float* __restrict__ A, const float* __restrict__ B,
           float* __restrict__ C, int M, int N, int K,
           long long sA, long long sB, long long sC,
           float alpha, float ident, int flags) {
  const int batch = blockIdx.z;
  A += (long long)batch * sA;
  B += (long long)batch * sB;
  float* Cb = C + (long long)batch * sC;
  __shared__ float As[16][68];
  __shared__ float Bs[16][68];
  const int tid = threadIdx.x;
  const int tx = tid & 15, ty = tid >> 4;
  const int m0 = blockIdx.y * 64, n0 = blockIdx.x * 64;
  float acc[4][4] = {};
  for (int k0 = 0; k0 < K; k0 += 16) {
    {
      int k = tid & 15;
      int mBase = tid >> 4;
#pragma unroll
      for (int i = 0; i < 4; i++) {
        int m = mBase + i * 16;
        int gm = m0 + m;
        As[k][m] = (gm < M) ? A[(long long)gm * K + (k0 + k)] : 0.f;
      }
    }
    {
      int n = tid & 63;
      int kBase = tid >> 6;
#pragma unroll
      for (int i = 0; i < 4; i++) {
        int k = kBase + i * 4;
        int gn = n0 + n;
        float vb = (gn < N) ? B[(long long)(k0 + k) * N + gn] : 0.f;
        if (flags & BG_BIDENT) vb = ident * ((k0 + k) == gn ? 1.f : 0.f) - vb;
        Bs[k][n] = vb;
      }
    }
    __syncthreads();
#pragma unroll
    for (int k = 0; k < 16; k++) {
      float a[4], b[4];
#pragma unroll
      for (int i = 0; i < 4; i++) a[i] = As[k][ty * 4 + i];
#pragma unroll
      for (int j = 0; j < 4; j++) b[j] = Bs[k][tx * 4 + j];
#pragma unroll
      for (int i = 0; i < 4; i++)
#pragma unroll
        for (int j = 0; j < 4; j++) acc[i][j] = fmaf(a[i], b[j], acc[i][j]);
    }
    __syncthreads();
  }
#pragma unroll
  for (int i = 0; i < 4; i++) {
    int gm = m0 + ty * 4 + i;
    if (gm >= M) continue;
#pragma unroll
    for (int j = 0; j < 4; j++) {
      int gn = n0 + tx * 4 + j;
      if (gn >= N) continue;
      Cb[(long long)gm * N + gn] = alpha * acc[i][j];
    }
  }
}

// ---------------- Wm = z @ O3, written transposed bf16 WmT[bh][d][k] -------
__global__ __launch_bounds__(256)
void wm_gemm(const float* __restrict__ Z, const float* __restrict__ O3,
             unsigned short* __restrict__ WmT) {
  const int batch = blockIdx.y;
  const int m0 = blockIdx.x * 64;
  const float* A = Z + (long long)batch * 65536;
  const float* B = O3 + (long long)batch * LM * DH;
  __shared__ float As[16][68];
  __shared__ float Bs[16][68];
  const int tid = threadIdx.x, tx = tid & 15, ty = tid >> 4;
  float acc[4][4] = {};
  for (int k0 = 0; k0 < 256; k0 += 16) {
    {
      int k = tid & 15, mB = tid >> 4;
#pragma unroll
      for (int i = 0; i < 4; i++) {
        int m = mB + i * 16;
        As[k][m] = A[(long long)(m0 + m) * 256 + k0 + k];
      }
    }
    {
      int n = tid & 63, kB = tid >> 6;
#pragma unroll
      for (int i = 0; i < 4; i++) {
        int k = kB + i * 4;
        Bs[k][n] = B[(long long)(k0 + k) * DH + n];
      }
    }
    __syncthreads();
#pragma unroll
    for (int k = 0; k < 16; k++) {
      float a[4], b[4];
#pragma unroll
      for (int i = 0; i < 4; i++) a[i] = As[k][ty * 4 + i];
#pragma unroll
      for (int j = 0; j < 4; j++) b[j] = Bs[k][tx * 4 + j];
#pragma unroll
      for (int i = 0; i < 4; i++)
#pragma unroll
        for (int j = 0; j < 4; j++) acc[i][j] = fmaf(a[i], b[j], acc[i][j]);
    }
    __syncthreads();
  }
#pragma unroll
  for (int i = 0; i < 4; i++)
#pragma unroll
    for (int j = 0; j < 4; j++)
      WmT[((long long)batch * DH + tx * 4 + j) * LM + m0 + ty * 4 + i] =
          f2bf(acc[i][j]);
}

// ---------------- row layernorm over 512 -> bf16 ----------------
__global__ __launch_bounds__(256)
void layernorm_rows_bf16(const float* __restrict__ X, const float* __restrict__ g,
                         const float* __restrict__ bt,
                         unsigned short* __restrict__ Y) {
  __shared__ float sm[4];
  long long r = blockIdx.x;
  const float* x = X + r * DIM;
  int t = threadIdx.x;
  float v0 = x[t], v1 = x[t + 256];
  float mu = blockReduceSum256(v0 + v1, sm) * (1.f / DIM);
  float d0 = v0 - mu, d1 = v1 - mu;
  float var = blockReduceSum256(d0 * d0 + d1 * d1, sm) * (1.f / DIM);
  float rs = 1.0f / sqrtf(var + 1e-5f);
  unsigned short* y = Y + r * DIM;
  y[t] = f2bf(d0 * rs * g[t] + bt[t]);
  y[t + 256] = f2bf(d1 * rs * g[t + 256] + bt[t + 256]);
}

// ---------------- landmark means from bf16 q,k ----------------
__global__ __launch_bounds__(64)
void landmarks_k(const unsigned short* __restrict__ q,
                 const unsigned short* __restrict__ k,
                 float* __restrict__ ql, float* __restrict__ kl,
                 unsigned short* __restrict__ qlb,
                 unsigned short* __restrict__ klb) {
  int bh = blockIdx.x >> 8, i = blockIdx.x & 255, d = threadIdx.x;
  long long base = ((long long)bh * NF + i * 32) * DH + d;
  float sq = 0.f, sk = 0.f;
#pragma unroll 4
  for (int l = 0; l < 32; l++) {
    sq += bf2f(q[base + (long long)l * DH]);
    sk += bf2f(k[base + (long long)l * DH]);
  }
  long long o = ((long long)bh * LM + i) * DH + d;
  float mq = sq * (1.f / 32.f), mk = sk * (1.f / 32.f);
  ql[o] = mq; kl[o] = mk;
  qlb[o] = f2bf(mq); klb[o] = f2bf(mk);
}

// ---------------- sim2 + row softmax -> attn2 (fp32 + bf16) ----------------
__global__ __launch_bounds__(256)
void sim2_softmax(const float* __restrict__ ql, const float* __restrict__ kl,
                  float* __restrict__ a2, unsigned short* __restrict__ a2b) {
  __shared__ float qs[64];
  __shared__ float sm[4];
  int bh = blockIdx.x >> 8, i = blockIdx.x & 255, t = threadIdx.x;
  if (t < 64) qs[t] = ql[((long long)bh * LM + i) * DH + t];
  __syncthreads();
  const float* krow = kl + (long long)bh * LM * DH + (long long)t * DH;
  float s = 0.f;
#pragma unroll
  for (int d = 0; d < 64; d++) s += qs[d] * krow[d];
  float m = blockReduceMax256(s, sm);
  float e = expf(s - m);
  float sum = blockReduceSum256(e, sm);
  long long off = ((long long)bh * LM + i) * LM + t;
  float v = e / sum;
  a2[off] = v;
  a2b[off] = f2bf(v);
}

// ---------------- pinv global scale reduction (col sums only) --------------
// softmax rows sum to exactly 1 -> the ref's row-sum max factor == 1.
__global__ __launch_bounds__(256)
void pinv_reduce(const float* __restrict__ a2, unsigned* __restrict__ red) {
  __shared__ float sm[4];
  int bh = blockIdx.x, t = threadIdx.x;
  const float* A = a2 + (long long)bh * LM * LM;
  float cs = 0.f;
  for (int i = 0; i < 256; i++) cs += fabsf(A[i * 256 + t]);
  float cm = blockReduceMax256(cs, sm);
  if (t == 0) atomicMax(&red[1], __float_as_uint(cm));
}

// ---------------- depthwise conv residual -> bf16 scattered ----------------
__global__ __launch_bounds__(256)
void conv_res_bf16(const unsigned short* __restrict__ vt,
                   const float* __restrict__ cw,
                   unsigned short* __restrict__ out) {
  int bh = blockIdx.x >> 6, tile = blockIdx.x & 63;
  int b = bh >> 3, hh = bh & 7;
  int t = threadIdx.x;
  int d = t & 63, pg = t >> 6;
  float wr[33];
#pragma unroll
  for (int kk = 0; kk < 33; kk++) wr[kk] = cw[hh * 33 + kk];
  const unsigned short* src = &vt[((long long)bh * DH + d) * NF];
  int base = tile * 128 + pg * 32;
  int n0 = base - 16;
  float win[64];
#pragma unroll
  for (int jj = 0; jj < 8; jj++) {
    int c = n0 + jj * 8;
    if (c >= 0 && c + 7 < NF) {
      short8 v = *(const short8*)&src[c];
#pragma unroll
      for (int j = 0; j < 8; j++)
        win[jj * 8 + j] = bf2f((unsigned short)v[j]);
    } else {
#pragma unroll
      for (int j = 0; j < 8; j++) {
        int nn = c + j;
        win[jj * 8 + j] = (nn >= 0 && nn < NF) ? bf2f(src[nn]) : 0.f;
      }
    }
  }
  unsigned short* dst = &out[((long long)(b * NF + base)) * DIM + hh * DH + d];
#pragma unroll
  for (int p = 0; p < 32; p++) {
    float s = 0.f;
#pragma unroll
    for (int kk = 0; kk < 33; kk++) s = fmaf(wr[kk], win[p + kk], s);
    dst[(long long)p * DIM] = f2bf(s);
  }
}

// ---------------- final LN(row0) @ w2 + b2 ----------------
__global__ __launch_bounds__(256)
void final_head(const float* __restrict__ X, const float* __restrict__ g,
                const float* __restrict__ bt, const float* __restrict__ w2,
                const float* __restrict__ b2, float* __restrict__ out) {
  __shared__ float sm[4];
  int b = blockIdx.x, t = threadIdx.x;
  const float* row = X + (long long)b * NF * DIM;
  float v0 = row[t], v1 = row[t + 256];
  float mu = blockReduceSum256(v0 + v1, sm) * (1.f / DIM);
  float d0 = v0 - mu, d1 = v1 - mu;
  float var = blockReduceSum256(d0 * d0 + d1 * d1, sm) * (1.f / DIM);
  float rs = 1.0f / sqrtf(var + 1e-5f);
  float y0 = d0 * rs * g[t] + bt[t];
  float y1 = d1 * rs * g[t + 256] + bt[t + 256];
  float l0 = y0 * w2[t * 2 + 0] + y1 * w2[(t + 256) * 2 + 0];
  float l1 = y0 * w2[t * 2 + 1] + y1 * w2[(t + 256) * 2 + 1];
  l0 = blockReduceSum256(l0, sm);
  l1 = blockReduceSum256(l1, sm);
  if (t == 0) {
    out[b * 2 + 0] = l0 + b2[0];
    out[b * 2 + 1] = l1 + b2[1];
  }
}

extern "C" void kernel_launch(void* const* d_in, const int* in_sizes, int n_in,
                              void* d_out, int out_size, void* d_ws,
                              size_t ws_size, hipStream_t stream) {
  const float* h      = (const float*)d_in[0];
  const float* w1     = (const float*)d_in[1];
  const float* b1     = (const float*)d_in[2];
  const float* cls    = (const float*)d_in[3];
  const float* ln_g   = (const float*)d_in[4];
  const float* ln_b   = (const float*)d_in[5];
  const float* w_qkv  = (const float*)d_in[6];
  const float* w_out  = (const float*)d_in[7];
  const float* b_out  = (const float*)d_in[8];
  const float* conv_w = (const float*)d_in[9];
  const float* fn_g   = (const float*)d_in[10];
  const float* fn_b   = (const float*)d_in[11];
  const float* w2     = (const float*)d_in[12];
  const float* b2     = (const float*)d_in[13];

  float* ws = (float*)d_ws;
  const long long XSZ = (long long)2 * NF * DIM;      // 8388608
  const long long QSZ = (long long)BHN * NF * DH;     // 8388608
  float* X  = ws;                                     // 8.4M f
  unsigned short* STAGE = (unsigned short*)(X + XSZ); // staging us region
  unsigned short* HB   = STAGE;                 // embed bf16
  unsigned short* XNB1 = STAGE;                 // LN out bf16
  unsigned short* XNB2 = STAGE;                 // attn out bf16 (XNB1 dead)
  unsigned short* VB   = STAGE + XSZ;           // V row-major temp
  unsigned short* XNC  = STAGE + XSZ;           // conv bf16 (VB dead)
  unsigned short* QB = STAGE + 2 * XSZ;
  unsigned short* KB = QB + QSZ;
  unsigned short* VT = KB + QSZ;                // d-major
  float* QL = (float*)(VT + QSZ);
  float* KL = QL + 262144;
  unsigned short* QLB = (unsigned short*)(KL + 262144);
  unsigned short* KLB = QLB + 262144;
  float* A2 = (float*)(KLB + 262144);           // fp32 attn2 (reduce + it5)
  float* ZA = A2 + 1048576;                     // final fp32 z (wm_gemm)
  float* ZB = ZA + 1048576;                     // z4 fp32 (it5 input)
  float* P  = ZB + 1048576;                     // it5 fp32 temps
  float* T1 = P + 1048576;
  float* T2 = T1 + 1048576;
  float* Mpart = T2 + 1048576;                  // 65536 f (unused slot)
  float* Lpart = Mpart + 65536;                 // 65536 f
  float* O3 = Lpart + 65536;                    // 262144 f
  unsigned short* WmB = (unsigned short*)(O3 + 262144);  // 262144 us
  unsigned* RED = (unsigned*)(WmB + 262144);    // [unused, colmax, pad, pad]
  unsigned short* WT = (unsigned short*)(RED + 4);
  unsigned short* W1T = WT;                     // 524288 us
  unsigned short* WQ0 = W1T + 524288;           // 786432
  unsigned short* WQ1 = WQ0 + 786432;           // 786432
  unsigned short* WO0 = WQ1 + 786432;           // 262144
  unsigned short* WO1 = WO0 + 262144;           // 262144

  // Aliases with disjoint liveness inside the VB/XNC slot (16.77 MB):
  //   VB (qkv->vt) -> A2B (sim2->pinv it4 S1) -> Opart (attn3->merge) -> XNC
  unsigned short* A2B = VB;                     // bf16 attn2 (pinv A-operand)
  float* Opart = (float*)VB;                    // 16*16*256*64 f = 16.77 MB
  // bf16 pinv buffers alias fp32 it5 temps (live only during it0..4):
  unsigned short* Zan = (unsigned short*)P;     // z even-iter (normal)
  unsigned short* Zat = Zan + 1048576;          // z even-iter (transposed)
  unsigned short* Zbn = (unsigned short*)ZB;    // z odd-iter
  unsigned short* Zbt = Zbn + 1048576;
  unsigned short* Pn  = (unsigned short*)T1;    // P = A2@z
  unsigned short* Pt  = Pn + 1048576;
  unsigned short* T1t = (unsigned short*)T2;    // bracket temps (B-operand only)
  unsigned short* T2t = T1t + 1048576;

  // ---- prologue: cls, h cast, all weight transposes, embed ----
  write_cls<<<4, 256, 0, stream>>>(cls, X);
  cvt_bf16<<<16382, 256, 0, stream>>>(h, HB, (long long)16382 * 1024);
  cvt_transpose<<<dim3(512 / 32, 1024 / 32), 256, 0, stream>>>(w1, W1T, 1024, 512);
  cvt_transpose<<<dim3(1536 / 32, 512 / 32), 256, 0, stream>>>(w_qkv, WQ0, 512, 1536);
  cvt_transpose<<<dim3(1536 / 32, 512 / 32), 256, 0, stream>>>(
      w_qkv + (long long)DIM * 1536, WQ1, 512, 1536);
  cvt_transpose<<<dim3(512 / 32, 512 / 32), 256, 0, stream>>>(w_out, WO0, 512, 512);
  cvt_transpose<<<dim3(512 / 32, 512 / 32), 256, 0, stream>>>(
      w_out + (long long)DIM * DIM, WO1, 512, 512);
  gemm_mfma<0><<<dim3(2, 128), 512, 0, stream>>>(HB, W1T, b1, X, nullptr, nullptr,
                                                 16382, 512, 1024,
                                                 MG_RELU | MG_BIAS, 1);

  for (int L = 0; L < 2; L++) {
    layernorm_rows_bf16<<<2 * NF, 256, 0, stream>>>(X, ln_g + L * DIM,
                                                    ln_b + L * DIM, XNB1);
    gemm_mfma<0><<<dim3(6, 128), 512, 0, stream>>>(XNB1, L ? WQ1 : WQ0, nullptr,
                                                   nullptr, QB, VB, 16384, 1536,
                                                   512, 0, 2);
    vt_transpose<<<BHN * 128, 256, 0, stream>>>(VB, VT);

    landmarks_k<<<BHN * LM, 64, 0, stream>>>(QB, KB, QL, KL, QLB, KLB);
    sim2_softmax<<<BHN * LM, 256, 0, stream>>>(QL, KL, A2, A2B);
    hipMemsetAsync(RED, 0, 16, stream);
    pinv_reduce<<<BHN, 256, 0, stream>>>(A2, RED);
    zinit<<<4096, 256, 0, stream>>>(A2, RED, Zan, Zat);
    for (int it = 0; it < 5; it++) {  // bf16 iterations (NS self-corrects)
      const unsigned short* zcn = (it & 1) ? Zbn : Zan;
      const unsigned short* zct = (it & 1) ? Zbt : Zat;
      unsigned short* znn = (it & 1) ? Zan : Zbn;
      unsigned short* znt = (it & 1) ? Zat : Zbt;
      // P = A2 @ z
      pinv_bf<<<dim3(8, 8, BHN), 256, 0, stream>>>(
          A2B, zct, Pn, Pt, nullptr, 1.f, 0.f, 1.f, PV_CN | PV_CT);
      // T1 = 7P - P@P
      pinv_bf<<<dim3(8, 8, BHN), 256, 0, stream>>>(
          Pn, Pt, nullptr, T1t, nullptr, 1.f, 7.f, -1.f, PV_CT | PV_ID);
      // T2 = 15P - P@T1
      pinv_bf<<<dim3(8, 8, BHN), 256, 0, stream>>>(
          Pn, T1t, nullptr, T2t, nullptr, 1.f, 15.f, -1.f, PV_CT | PV_ID);
      // zn = 0.25*(13z - z@T2); it==4 writes fp32 z4 for the fp32 iteration
      if (it < 4)
        pinv_bf<<<dim3(8, 8, BHN), 256, 0, stream>>>(
            zcn, T2t, znn, znt, nullptr, 0.25f, 13.f, -1.f,
            PV_CN | PV_CT | PV_ID);
      else
        pinv_bf<<<dim3(8, 8, BHN), 256, 0, stream>>>(
            zcn, T2t, nullptr, nullptr, ZB, 0.25f, 13.f, -1.f, PV_CF | PV_ID);
    }
    // final iteration fp32
    bgemm<<<dim3(4, 4, BHN), 256, 0, stream>>>(A2, ZB, P, 256, 256, 256,
                                               65536, 65536, 65536, 1.f, 0.f, 0);
    bgemm<<<dim3(4, 4, BHN), 256, 0, stream>>>(P, P, T1, 256, 256, 256,
                                               65536, 65536, 65536, 1.f, 7.f,
                                               BG_BIDENT);
    bgemm<<<dim3(4, 4, BHN), 256, 0, stream>>>(P, T1, T2, 256, 256, 256,
                                               65536, 65536, 65536, 1.f, 15.f,
                                               BG_BIDENT);
    bgemm<<<dim3(4, 4, BHN), 256, 0, stream>>>(ZB, T2, ZA, 256, 256, 256,
                                               65536, 65536, 65536, 0.25f,
                                               13.f, BG_BIDENT);
    // final z in ZA

    // ---- fused attn3: LDS-resident chunks; plain (O,L) partials -> O3 ----
    flash_attn3<<<dim3(16, BHN), 512, 0, stream>>>(QLB, KB, VT, Opart, Lpart);
    attn3_merge<<<1024, 256, 0, stream>>>(Opart, Lpart, O3);

    // WmT(bf16) = (z @ O3)^T
    wm_gemm<<<dim3(4, BHN), 256, 0, stream>>>(ZA, O3, WmB);

    // conv residual (bf16) into XNC (overwrites dead Opart)
    conv_res_bf16<<<BHN * 64, 256, 0, stream>>>(VT, conv_w + L * 264, XNC);

    // ---- fused attn1 (LDS-resident K+Wm): XNB2 = bf16(conv + attn1@Wm) ----
    flash_attn1<<<dim3(32, BHN), 512, 0, stream>>>(QB, KLB, WmB, XNC, XNB2);

    // ---- X += XNB2 @ w_out + b_out ----
    gemm_mfma<1><<<dim3(2, 128), 512, 0, stream>>>(XNB2, L ? WO1 : WO0,
                                                   b_out + L * DIM, X, nullptr,
                                                   nullptr, 16384, 512, 512,
                                                   MG_ADDC | MG_BIAS, 0);
  }
  final_head<<<2, 256, 0, stream>>>(X, fn_g, fn_b, w2, b2, (float*)d_out);
}

// Round 13
// 1202.299 us; speedup vs baseline: 1.1016x; 1.0014x over previous
//
#include <hip/hip_runtime.h>
#include <hip/hip_bf16.h>

#define DIM 512
#define HEADS 8
#define DH 64
#define LM 256
#define NF 8192
#define BHN 16   // batch(2) * heads(8)

typedef __attribute__((ext_vector_type(8))) short short8;
typedef __attribute__((ext_vector_type(4))) float f32x4;

__device__ __forceinline__ float bf2f(unsigned short u) {
  return __uint_as_float((unsigned)u << 16);
}
__device__ __forceinline__ unsigned short f2bf(float x) {
  unsigned u = __float_as_uint(x);
  unsigned r = u + 0x7fffu + ((u >> 16) & 1u);
  return (unsigned short)(r >> 16);
}

// async global->LDS, 16B per lane; lds dest = wave-uniform base + lane*16
__device__ __forceinline__ void gl2lds16(const void* g, void* l) {
  __builtin_amdgcn_global_load_lds(
      (const __attribute__((address_space(1))) void*)g,
      (__attribute__((address_space(3))) void*)l, 16, 0, 0);
}

// LDS-only fence: wait ds ops, then block scheduler from hoisting MFMAs
// above the wait (rule: inline-asm lgkmcnt needs a following sched_barrier).
__device__ __forceinline__ void lds_fence() {
  asm volatile("s_waitcnt lgkmcnt(0)" ::: "memory");
  __builtin_amdgcn_sched_barrier(0);
}

// ---------------- reduction helpers ----------------
__device__ __forceinline__ float waveReduceSum(float v) {
#pragma unroll
  for (int o = 1; o < 64; o <<= 1) v += __shfl_xor(v, o);
  return v;
}
__device__ __forceinline__ float waveReduceMax(float v) {
#pragma unroll
  for (int o = 1; o < 64; o <<= 1) v = fmaxf(v, __shfl_xor(v, o));
  return v;
}
__device__ __forceinline__ float blockReduceSum256(float v, float* sm) {
  v = waveReduceSum(v);
  int w = threadIdx.x >> 6;
  __syncthreads();
  if ((threadIdx.x & 63) == 0) sm[w] = v;
  __syncthreads();
  return sm[0] + sm[1] + sm[2] + sm[3];
}
__device__ __forceinline__ float blockReduceMax256(float v, float* sm) {
  v = waveReduceMax(v);
  int w = threadIdx.x >> 6;
  __syncthreads();
  if ((threadIdx.x & 63) == 0) sm[w] = v;
  __syncthreads();
  return fmaxf(fmaxf(sm[0], sm[1]), fmaxf(sm[2], sm[3]));
}

// ---------------- casts ----------------
__global__ __launch_bounds__(256)
void cvt_bf16(const float* __restrict__ in, unsigned short* __restrict__ out,
              long long n) {
  long long i = ((long long)blockIdx.x * 256 + threadIdx.x) * 4;
  if (i + 3 < n) {
    float4 v = *(const float4*)&in[i];
    ushort4 o;
    o.x = f2bf(v.x); o.y = f2bf(v.y); o.z = f2bf(v.z); o.w = f2bf(v.w);
    *(ushort4*)&out[i] = o;
  } else {
    for (; i < n; i++) out[i] = f2bf(in[i]);
  }
}

// transpose+cast: in fp32 [K][N] -> out bf16 [N][K]
__global__ __launch_bounds__(256)
void cvt_transpose(const float* __restrict__ in, unsigned short* __restrict__ out,
                   int Kd, int Nd) {
  __shared__ float t[32][33];
  int x = threadIdx.x & 31, y = threadIdx.x >> 5;
#pragma unroll
  for (int i = 0; i < 32; i += 8) {
    int k = blockIdx.y * 32 + y + i, n = blockIdx.x * 32 + x;
    t[y + i][x] = in[(long long)k * Nd + n];
  }
  __syncthreads();
#pragma unroll
  for (int i = 0; i < 32; i += 8) {
    int n = blockIdx.x * 32 + y + i, k = blockIdx.y * 32 + x;
    out[(long long)n * Kd + k] = f2bf(t[x][y + i]);
  }
}

// VB [bh][n][d] bf16 -> VT [bh][d][n] bf16
__global__ __launch_bounds__(256)
void vt_transpose(const unsigned short* __restrict__ VB,
                  unsigned short* __restrict__ VT) {
  __shared__ unsigned short t[64][80];
  int bh = blockIdx.x >> 7, tile = blockIdx.x & 127;
  int n0 = tile * 64;
  int tid = threadIdx.x;
#pragma unroll
  for (int it = 0; it < 2; it++) {
    int s = it * 256 + tid;
    int nl = s >> 3, sg = s & 7;
    *(short8*)&t[nl][sg * 8] =
        *(const short8*)&VB[((long long)bh * NF + n0 + nl) * DH + sg * 8];
  }
  __syncthreads();
#pragma unroll
  for (int it = 0; it < 2; it++) {
    int s = it * 256 + tid;
    int dl = s >> 3, sg = s & 7;
    short8 v;
#pragma unroll
    for (int j = 0; j < 8; j++) ((unsigned short*)&v)[j] = t[sg * 8 + j][dl];
    *(short8*)&VT[((long long)bh * DH + dl) * NF + n0 + sg * 8] = v;
  }
}

// ---------------- cls row write ----------------
__global__ __launch_bounds__(256) void write_cls(const float* __restrict__ cls,
                                                 float* __restrict__ X) {
  int t = blockIdx.x * 256 + threadIdx.x;
  int b = t >> 9, c = t & 511;
  X[(long long)b * NF * DIM + c] = cls[c];
}

// ---------------- bf16 MFMA GEMM (projections) ----------------------------
// r13: 128x256 tile, 8 waves, DEPTH-buffer counted-vmcnt pipeline (T4).
// Per step: {stage(t+DEPTH-1); vmcnt(3*inflight); s_barrier; ds+MFMA;
// s_barrier} -- up to DEPTH-1 tiles stay in flight, 2 compute phases cover
// each load's latency at DEPTH=3. Embed/wout (grid 256 = 1 block/CU, no
// TLP) use DEPTH=3 (72KB LDS, free at 1 blk/CU); qkv keeps DEPTH=2 (48KB,
// 3 blks/CU). r12: counted-vmcnt at 1 blk/CU was the lever (55->45us).
#define MG_RELU 1
#define MG_ADDC 2
#define MG_BIAS 4
// remap: 0 plain fp32, 1 embed scatter fp32, 2 qkv -> bf16 QB/KB/VB (vector)
template <int PRE, int DEPTH>
__global__ __launch_bounds__(512)
void gemm_mfma(const unsigned short* __restrict__ A,
               const unsigned short* __restrict__ B,
               const float* __restrict__ bias, float* __restrict__ C,
               unsigned short* __restrict__ qkv, unsigned short* __restrict__ vbuf,
               int M, int N, int K, int flags, int remap) {
  __shared__ short8 smem[DEPTH * 1536];  // DEPTH x (A 8KB + B 16KB)
  const int tid = threadIdx.x;
  const int lane = tid & 63, wave = tid >> 6;     // wave 0..7
  const int wm = wave >> 2, wn = wave & 3;        // 2 x 4 wave grid
  const int nwg = gridDim.x * gridDim.y;
  const int orig = blockIdx.y * gridDim.x + blockIdx.x;
  const int swz = ((nwg & 7) == 0) ? (orig & 7) * (nwg >> 3) + (orig >> 3) : orig;
  const int m0 = (swz / gridDim.x) * 128, n0 = (swz % gridDim.x) * 256;
  const int r16 = lane & 15, quad = lane >> 4;
  const unsigned short* pa  = A + (long long)(m0 + 16 * wave + r16) * K + quad * 8;
  const unsigned short* pb0 = B + (long long)(n0 + 32 * wave + r16) * K + quad * 8;
  const unsigned short* pb1 = B + (long long)(n0 + 32 * wave + 16 + r16) * K + quad * 8;
  auto stage = [&](int bsel) {
    short8* Als = smem + bsel * 1536;        // [8][64] (8KB)
    short8* Bls = smem + bsel * 1536 + 512;  // [16][64] (16KB)
    gl2lds16(pa, Als + wave * 64);
    gl2lds16(pb0, Bls + (2 * wave) * 64);
    gl2lds16(pb1, Bls + (2 * wave + 1) * 64);
    pa += 32; pb0 += 32; pb1 += 32;
  };
  // C prefetch (ADDC only, remap==0): issue 32 of the 64 per-lane C reads
  // BEFORE the K-loop; they complete under the first tile wait. Bit-identical.
  float cpre[2][4][4];
  if (PRE && (flags & MG_ADDC)) {
#pragma unroll
    for (int mt = 0; mt < 2; mt++)
#pragma unroll
      for (int nt = 0; nt < 4; nt++)
#pragma unroll
        for (int r = 0; r < 4; r++) {
          int gm = m0 + wm * 64 + mt * 16 + quad * 4 + r;
          int gn = n0 + wn * 64 + nt * 16 + r16;
          cpre[mt][nt][r] = C[(long long)gm * N + gn];
        }
  }
  f32x4 acc[4][4] = {};
  const int nsteps = K >> 5;  // 16 or 32 (>= DEPTH)
#pragma unroll
  for (int d = 0; d < DEPTH - 1; d++) stage(d);
  for (int t = 0; t < nsteps; t++) {
    if (t + DEPTH - 1 < nsteps) stage((t + DEPTH - 1) % DEPTH);
    // wait: tile t landed; up to 'inflight' newer tiles (3 loads each) fly.
    int inflight = nsteps - 1 - t;
    if (inflight > DEPTH - 1) inflight = DEPTH - 1;
    if (inflight >= 2) {
      asm volatile("s_waitcnt vmcnt(6)" ::: "memory");
    } else if (inflight == 1) {
      asm volatile("s_waitcnt vmcnt(3)" ::: "memory");
    } else {
      asm volatile("s_waitcnt vmcnt(0)" ::: "memory");
    }
    __builtin_amdgcn_sched_barrier(0);
    __builtin_amdgcn_s_barrier();  // all waves: buf(t) fully written
    short8* Als = smem + (t % DEPTH) * 1536;
    short8* Bls = smem + (t % DEPTH) * 1536 + 512;
    short8 af[4], bfr[4];
#pragma unroll
    for (int mt = 0; mt < 4; mt++) af[mt] = Als[(wm * 4 + mt) * 64 + lane];
#pragma unroll
    for (int nt = 0; nt < 4; nt++) bfr[nt] = Bls[(wn * 4 + nt) * 64 + lane];
#pragma unroll
    for (int mt = 0; mt < 4; mt++)
#pragma unroll
      for (int nt = 0; nt < 4; nt++)
        acc[mt][nt] = __builtin_amdgcn_mfma_f32_16x16x32_bf16(
            af[mt], bfr[nt], acc[mt][nt], 0, 0, 0);
    __builtin_amdgcn_s_barrier();  // reads of buf(t) done before overwrite
  }
  if (remap == 2) {
    // Ep aliases the staging memory (safe: final vmcnt(0)+barrier drained all)
    unsigned short (*Ep)[32][64] = (unsigned short (*)[32][64])smem;  // 8x4KB
    int gn_base = n0 + wn * 64;
    int s = gn_base >> 9, hh = (gn_base >> 6) & 7;
    float scale = (s == 0) ? 0.125f : 1.f;
    unsigned short* basep =
        (s == 0) ? qkv : (s == 1) ? qkv + (long long)BHN * NF * DH : vbuf;
#pragma unroll
    for (int half = 0; half < 2; half++) {
      lds_fence();  // prior half's Ep reads drained (wave-local region)
#pragma unroll
      for (int mt = half * 2; mt < half * 2 + 2; mt++)
#pragma unroll
        for (int nt = 0; nt < 4; nt++)
#pragma unroll
          for (int r = 0; r < 4; r++)
            Ep[wave][(mt & 1) * 16 + quad * 4 + r][nt * 16 + r16] =
                f2bf(acc[mt][nt][r] * scale);
      lds_fence();
#pragma unroll
      for (int it = 0; it < 4; it++) {
        int idx = it * 64 + lane;
        int m_l = idx >> 3, sg = idx & 7;
        int gm = m0 + wm * 64 + half * 32 + m_l;
        int b = gm >> 13, n = gm & (NF - 1);
        int bh = b * HEADS + hh;
        short8 v = *(short8*)&Ep[wave][m_l][sg * 8];
        *(short8*)&basep[((long long)bh * NF + n) * DH + sg * 8] = v;
      }
    }
  } else {
#pragma unroll
    for (int mt = 0; mt < 4; mt++) {
#pragma unroll
      for (int nt = 0; nt < 4; nt++) {
#pragma unroll
        for (int r = 0; r < 4; r++) {
          int gm = m0 + wm * 64 + mt * 16 + quad * 4 + r;
          int gn = n0 + wn * 64 + nt * 16 + r16;
          if (gm >= M) continue;
          float v = acc[mt][nt][r];
          if (flags & MG_BIAS) v += bias[gn];
          long long idx;
          if (remap == 1) {
            int b = gm / 8191;
            int n = gm - b * 8191;
            idx = ((long long)(b * NF + 1 + n)) * DIM + gn;
          } else {
            idx = (long long)gm * N + gn;
          }
          if (flags & MG_ADDC) {
            if (PRE && mt < 2) v += cpre[mt][nt][r];
            else v += C[idx];
          }
          if (flags & MG_RELU) v = fmaxf(v, 0.f);
          C[idx] = v;
        }
      }
    }
  }
}

// ---------------- fused attn1: LDS-resident K_landmark + Wm ---------------
// K (256x64, 32KB) and Wm (64x256, 32KB) staged ONCE per block via
// global_load_lds with XOR swizzle (LDS[row][c] = G[row][c^(row&7)], 16B
// units) -> all MFMA operands come from conflict-free LDS. 512 thr, 8
// waves x 2 row-tiles; 1 block/CU (98KB LDS). No-max softmax + ones-MFMA
// row sums.
__global__ __launch_bounds__(512)
void flash_attn1(const unsigned short* __restrict__ QB,
                 const unsigned short* __restrict__ KLB,
                 const unsigned short* __restrict__ WmB,
                 const unsigned short* __restrict__ XNC,
                 unsigned short* __restrict__ XNB2) {
  __shared__ unsigned short Klds[LM * DH];     // 32 KB
  __shared__ unsigned short Wlds[DH * LM];     // 32 KB
  __shared__ unsigned short Plds[8][16][136];  // 34 KB
  const int bh = blockIdx.y, b = bh >> 3, hh = bh & 7;
  const int tid = threadIdx.x, lane = tid & 63, wave = tid >> 6;
  const int r16 = lane & 15, quad = lane >> 4;
  const unsigned short* Aq = QB + (long long)bh * NF * DH;
  const unsigned short* Kg = KLB + (long long)bh * LM * DH;
  const unsigned short* Wg = WmB + (long long)bh * DH * LM;
#pragma unroll
  for (int j = 0; j < 4; j++) {  // K: 32 x 1KB units
    int u = j * 8 + wave;
    int s = u * 64 + lane;
    int row = s >> 3, ck = s & 7;
    gl2lds16(Kg + row * DH + ((ck ^ (row & 7)) << 3), (char*)Klds + u * 1024);
  }
#pragma unroll
  for (int j = 0; j < 4; j++) {  // Wm: 32 x 1KB units
    int u = j * 8 + wave;
    int s = u * 64 + lane;
    int row = s >> 5, ck = s & 31;
    gl2lds16(Wg + row * LM + ((ck ^ (row & 7)) << 3), (char*)Wlds + u * 1024);
  }
  __syncthreads();
  short8 ones;
#pragma unroll
  for (int j = 0; j < 8; j++) ((unsigned short*)&ones)[j] = 0x3F80;  // bf16 1.0
#pragma unroll
  for (int rt = 0; rt < 2; rt++) {
    const int m0w = blockIdx.x * 256 + (wave * 2 + rt) * 16;
    short8 af[2];
#pragma unroll
    for (int kc = 0; kc < 2; kc++)
      af[kc] = *(const short8*)&Aq[(long long)(m0w + r16) * DH + kc * 32 + quad * 8];
    f32x4 O[4] = {};
    f32x4 Ls = {};
#pragma unroll
    for (int t = 0; t < 2; t++) {
      int c0 = t * 128;
      f32x4 S[8] = {};
      __builtin_amdgcn_s_setprio(1);
#pragma unroll
      for (int nt = 0; nt < 8; nt++) {
        int kl = c0 + nt * 16 + r16;
#pragma unroll
        for (int kc = 0; kc < 2; kc++) {
          short8 bb = *(const short8*)((const char*)Klds + kl * 128 +
                                       (((kc * 4 + quad) ^ (kl & 7)) << 4));
          S[nt] = __builtin_amdgcn_mfma_f32_16x16x32_bf16(af[kc], bb, S[nt], 0, 0, 0);
        }
      }
      __builtin_amdgcn_s_setprio(0);
#pragma unroll
      for (int nt = 0; nt < 8; nt++)
#pragma unroll
        for (int r = 0; r < 4; r++)
          Plds[wave][quad * 4 + r][nt * 16 + r16] = f2bf(__expf(S[nt][r]));
      lds_fence();
      __builtin_amdgcn_s_setprio(1);
#pragma unroll
      for (int kc = 0; kc < 4; kc++) {
        short8 a = *(short8*)&Plds[wave][r16][kc * 32 + quad * 8];
        Ls = __builtin_amdgcn_mfma_f32_16x16x32_bf16(a, ones, Ls, 0, 0, 0);
#pragma unroll
        for (int nt2 = 0; nt2 < 4; nt2++) {
          int wrow = nt2 * 16 + r16;
          int cu = (c0 >> 3) + kc * 4 + quad;
          short8 bb = *(const short8*)((const char*)Wlds + wrow * 512 +
                                       ((cu ^ (wrow & 7)) << 4));
          O[nt2] = __builtin_amdgcn_mfma_f32_16x16x32_bf16(a, bb, O[nt2], 0, 0, 0);
        }
      }
      __builtin_amdgcn_s_setprio(0);
    }
    float invl[4];
#pragma unroll
    for (int r = 0; r < 4; r++) invl[r] = 1.f / Ls[r];
#pragma unroll
    for (int nt2 = 0; nt2 < 4; nt2++)
#pragma unroll
      for (int r = 0; r < 4; r++) {
        int row = m0w + quad * 4 + r;
        int d = nt2 * 16 + r16;
        long long gi = ((long long)(b * NF + row)) * DIM + hh * DH + d;
        XNB2[gi] = f2bf(O[nt2][r] * invl[r] + bf2f(XNC[gi]));
      }
  }
}

// ---------------- fused attn3: LDS-resident K/V chunk pipeline ------------
// Block = (ks, bh): all 256 landmark rows vs a 512-col KV chunk, processed
// as 4 sub-chunks of 128 with double-buffered K(16KB)+V(16KB) staging
// (m97 pattern). No-max + ones-MFMA math.
__device__ __forceinline__ void stage_kv3(const unsigned short* Kg,
                                          const unsigned short* Vg,
                                          unsigned short* Kb, unsigned short* Vb,
                                          int kv0, int wave, int lane) {
#pragma unroll
  for (int j = 0; j < 2; j++) {
    int u = j * 8 + wave;
    int s = u * 64 + lane;
    int kr = s >> 3, kc = s & 7;
    gl2lds16(Kg + (long long)(kv0 + kr) * DH + ((kc ^ (kr & 7)) << 3),
             (char*)Kb + u * 1024);
    int vr = s >> 4, vc = s & 15;
    gl2lds16(Vg + (long long)vr * NF + kv0 + ((vc ^ (vr & 7)) << 3),
             (char*)Vb + u * 1024);
  }
}

__global__ __launch_bounds__(512)
void flash_attn3(const unsigned short* __restrict__ QLB,
                 const unsigned short* __restrict__ KB,
                 const unsigned short* __restrict__ VT,
                 float* __restrict__ Opart, float* __restrict__ Lpart) {
  __shared__ unsigned short Klds[2][128 * DH];  // 2 x 16 KB
  __shared__ unsigned short Vlds[2][DH * 128];  // 2 x 16 KB
  __shared__ unsigned short Plds[8][16][136];   // 34 KB
  const int ks = blockIdx.x, bh = blockIdx.y;
  const int tid = threadIdx.x, lane = tid & 63, wave = tid >> 6;
  const int r16 = lane & 15, quad = lane >> 4;
  const unsigned short* Aq = QLB + (long long)bh * LM * DH;
  const unsigned short* Kg = KB + (long long)bh * NF * DH;
  const unsigned short* Vg = VT + (long long)bh * DH * NF;
  short8 af2[2][2];
#pragma unroll
  for (int rt = 0; rt < 2; rt++) {
    int m0w = (wave * 2 + rt) * 16;
#pragma unroll
    for (int kc = 0; kc < 2; kc++)
      af2[rt][kc] =
          *(const short8*)&Aq[(long long)(m0w + r16) * DH + kc * 32 + quad * 8];
  }
  short8 ones;
#pragma unroll
  for (int j = 0; j < 8; j++) ((unsigned short*)&ones)[j] = 0x3F80;  // bf16 1.0
  f32x4 O2[2][4] = {};
  f32x4 Ls2[2] = {};
  stage_kv3(Kg, Vg, Klds[0], Vlds[0], ks * 512, wave, lane);
  __syncthreads();
  for (int t = 0; t < 4; t++) {
    int cb = t & 1;
    if (t < 3)
      stage_kv3(Kg, Vg, Klds[cb ^ 1], Vlds[cb ^ 1], ks * 512 + (t + 1) * 128,
                wave, lane);
    const unsigned short* Kb = Klds[cb];
    const unsigned short* Vb = Vlds[cb];
#pragma unroll
    for (int rt = 0; rt < 2; rt++) {
      f32x4 S[8] = {};
      __builtin_amdgcn_s_setprio(1);
#pragma unroll
      for (int nt = 0; nt < 8; nt++) {
        int kl = nt * 16 + r16;
#pragma unroll
        for (int kc = 0; kc < 2; kc++) {
          short8 bb = *(const short8*)((const char*)Kb + kl * 128 +
                                       (((kc * 4 + quad) ^ (kl & 7)) << 4));
          S[nt] = __builtin_amdgcn_mfma_f32_16x16x32_bf16(af2[rt][kc], bb, S[nt],
                                                          0, 0, 0);
        }
      }
      __builtin_amdgcn_s_setprio(0);
#pragma unroll
      for (int nt = 0; nt < 8; nt++)
#pragma unroll
        for (int r = 0; r < 4; r++)
          Plds[wave][quad * 4 + r][nt * 16 + r16] = f2bf(__expf(S[nt][r]));
      lds_fence();
      __builtin_amdgcn_s_setprio(1);
#pragma unroll
      for (int kc2 = 0; kc2 < 4; kc2++) {
        short8 a = *(short8*)&Plds[wave][r16][kc2 * 32 + quad * 8];
        Ls2[rt] = __builtin_amdgcn_mfma_f32_16x16x32_bf16(a, ones, Ls2[rt], 0, 0, 0);
#pragma unroll
        for (int nt2 = 0; nt2 < 4; nt2++) {
          int vr = nt2 * 16 + r16;
          int u = kc2 * 4 + quad;
          short8 bb = *(const short8*)((const char*)Vb + vr * 256 +
                                       ((u ^ (vr & 7)) << 4));
          O2[rt][nt2] = __builtin_amdgcn_mfma_f32_16x16x32_bf16(a, bb, O2[rt][nt2],
                                                                0, 0, 0);
        }
      }
      __builtin_amdgcn_s_setprio(0);
    }
    __syncthreads();
  }
  float* Ob = Opart + (((long long)ks * BHN + bh) * LM) * DH;
#pragma unroll
  for (int rt = 0; rt < 2; rt++) {
    int m0w = (wave * 2 + rt) * 16;
#pragma unroll
    for (int nt2 = 0; nt2 < 4; nt2++)
#pragma unroll
      for (int r = 0; r < 4; r++)
        Ob[(long long)(m0w + quad * 4 + r) * DH + nt2 * 16 + r16] = O2[rt][nt2][r];
    if (r16 == 0)
#pragma unroll
      for (int r = 0; r < 4; r++)
        Lpart[((long long)ks * BHN + bh) * LM + m0w + quad * 4 + r] = Ls2[rt][r];
  }
}

__global__ __launch_bounds__(256)
void attn3_merge(const float* __restrict__ Opart, const float* __restrict__ Lpart,
                 float* __restrict__ O3) {
  int idx = blockIdx.x * 256 + threadIdx.x;  // 262144
  int bh = idx >> 14, rem = idx & 16383;
  int row = rem >> 6, d = rem & 63;
  float L = 0.f, acc = 0.f;
#pragma unroll
  for (int c = 0; c < 16; c++) {
    L += Lpart[((long long)c * BHN + bh) * LM + row];
    acc += Opart[(((long long)c * BHN + bh) * LM + row) * DH + d];
  }
  O3[((long long)bh * LM + row) * DH + d] = acc / L;
}

// ---------------- z0 = attn2^T / rowmax; writes bf16 normal + transposed ---
__global__ __launch_bounds__(256)
void zinit(const float* __restrict__ a2, const unsigned* __restrict__ red,
           unsigned short* __restrict__ zn, unsigned short* __restrict__ zt) {
  // softmax rows sum to 1 exactly => ref's "col" factor == 1; scale = 1/colmax
  float scale = 1.0f / __uint_as_float(red[1]);
  long long idx = (long long)blockIdx.x * 256 + threadIdx.x;
  int bh = (int)(idx >> 16);
  int ij = (int)(idx & 65535);
  int i = ij >> 8, j = ij & 255;
  zn[idx] = f2bf(a2[((long long)bh << 16) + (j << 8) + i] * scale);
  zt[idx] = f2bf(a2[idx] * scale);
}

// ---------------- pinv bf16 GEMM, full-K staging, dual-layout output -------
// C = alpha * (ident * A[m][n] + beta * (A@B)[m][n]); B given TRANSPOSED.
// 32x32 tiles (grid 8x8x16 = 1024 blocks, 4 blocks/CU) for latency overlap.
#define PV_CN 1   // write Cn bf16 [m][n]
#define PV_CT 2   // write Ct bf16 [n][m]
#define PV_CF 4   // write Cf fp32 [m][n]
#define PV_ID 8   // include ident*A[m][n] term (A@I = A)
__global__ __launch_bounds__(256)
void pinv_bf(const unsigned short* __restrict__ An,
             const unsigned short* __restrict__ Bt,
             unsigned short* __restrict__ Cn, unsigned short* __restrict__ Ct,
             float* __restrict__ Cf, float alpha, float ident, float beta,
             int flags) {
  __shared__ unsigned short Als[32][256];  // 16 KB, XOR-swizzled chunks
  __shared__ unsigned short Bls[32][256];
  const int batch = blockIdx.z;
  An += (long long)batch * 65536;
  Bt += (long long)batch * 65536;
  const int tid = threadIdx.x, lane = tid & 63, wave = tid >> 6;
  const int wm2 = wave >> 1, wn2 = wave & 1;
  const int m0 = blockIdx.y * 32, n0 = blockIdx.x * 32;
  const int r16 = lane & 15, quad = lane >> 4;
  // one-shot full-K staging. LDS physical chunk g holds logical k-chunk
  // (g&31)^(row&7) of row g>>5 (pre-swizzled global source, linear LDS dest).
#pragma unroll
  for (int j = 0; j < 4; j++) {
    int g = (j * 4 + wave) * 64 + lane;  // 0..1023
    int row = g >> 5, plog = (g & 31) ^ (row & 7);
    gl2lds16(An + ((m0 + row) << 8) + plog * 8,
             (char*)Als + (j * 4 + wave) * 1024);
    gl2lds16(Bt + ((n0 + row) << 8) + plog * 8,
             (char*)Bls + (j * 4 + wave) * 1024);
  }
  __syncthreads();
  f32x4 acc = {};
  const int arow = wm2 * 16 + r16, brow = wn2 * 16 + r16;
#pragma unroll
  for (int kk = 0; kk < 8; kk++) {
    short8 af = *(const short8*)((const char*)Als + arow * 512 +
                                 ((kk * 4 + quad) ^ (arow & 7)) * 16);
    short8 bfr = *(const short8*)((const char*)Bls + brow * 512 +
                                  ((kk * 4 + quad) ^ (brow & 7)) * 16);
    acc = __builtin_amdgcn_mfma_f32_16x16x32_bf16(af, bfr, acc, 0, 0, 0);
  }
  long long cb = (long long)batch * 65536;
  int ncol = n0 + wn2 * 16 + r16;
  float vals[4];
#pragma unroll
  for (int r = 0; r < 4; r++) {
    int mrow = wm2 * 16 + quad * 4 + r;  // local row in [0,32)
    float v = beta * acc[r];
    if (flags & PV_ID) {
      // A[m][n] read back from the staged (swizzled) A tile
      unsigned short a = *(const unsigned short*)(
          (const char*)Als + mrow * 512 +
          (((ncol >> 3) ^ (mrow & 7)) * 16) + (ncol & 7) * 2);
      v += ident * bf2f(a);
    }
    vals[r] = v * alpha;
    int gm = m0 + mrow;
    if (flags & PV_CN) Cn[cb + ((long long)gm << 8) + ncol] = f2bf(vals[r]);
    if (flags & PV_CF) Cf[cb + ((long long)gm << 8) + ncol] = vals[r];
  }
  if (flags & PV_CT) {
    ushort4 o;
    o.x = f2bf(vals[0]); o.y = f2bf(vals[1]);
    o.z = f2bf(vals[2]); o.w = f2bf(vals[3]);
    *(ushort4*)&Ct[cb + ((long long)ncol << 8) + m0 + wm2 * 16 + quad * 4] = o;
  }
}

// ---------------- batched GEMM (fp32: last pinv iter) ----------------
#define BG_BIDENT 16
__global__ __launch_bounds__(256)
void bgemm(const float* __restrict__ A, const float* __restrict__ B,
           float* __restrict__ C, int M, int N, int K,
           long long sA, long long sB, long long sC,
           float alpha, float ident, int flags) {
  const int batch = blockIdx.z;
  A += (long long)batch * sA;
  B += (long long)batch * sB;
  float* Cb = C + (long long)batch * sC;
  __shared__ float As[16][68];
  __shared__ float Bs[16][68];
  const int tid = threadIdx.x;
  const int tx = tid & 15, ty = tid >> 4;
  const int m0 = blockIdx.y * 64, n0 = blockIdx.x * 64;
  float acc[4][4] = {};
  for (int k0 = 0; k0 < K; k0 += 16) {
    {
      int k = tid & 15;
      int mBase = tid >> 4;
#pragma unroll
      for (int i = 0; i < 4; i++) {
        int m = mBase + i * 16;
        int gm = m0 + m;
        As[k][m] = (gm < M) ? A[(long long)gm * K + (k0 + k)] : 0.f;
      }
    }
    {
      int n = tid & 63;
      int kBase = tid >> 6;
#pragma unroll
      for (int i = 0; i < 4; i++) {
        int k = kBase + i * 4;
        int gn = n0 + n;
        float vb = (gn < N) ? B[(long long)(k0 + k) * N + gn] : 0.f;
        if (flags & BG_BIDENT) vb = ident * ((k0 + k) == gn ? 1.f : 0.f) - vb;
        Bs[k][n] = vb;
      }
    }
    __syncthreads();
#pragma unroll
    for (int k = 0; k < 16; k++) {
      float a[4], b[4];
#pragma unroll
      for (int i = 0; i < 4; i++) a[i] = As[k][ty * 4 + i];
#pragma unroll
      for (int j = 0; j < 4; j++) b[j] = Bs[k][tx * 4 + j];
#pragma unroll
      for (int i = 0; i < 4; i++)
#pragma unroll
        for (int j = 0; j < 4; j++) acc[i][j] = fmaf(a[i], b[j], acc[i][j]);
    }
    __syncthreads();
  }
#pragma unroll
  for (int i = 0; i < 4; i++) {
    int gm = m0 + ty * 4 + i;
    if (gm >= M) continue;
#pragma unroll
    for (int j = 0; j < 4; j++) {
      int gn = n0 + tx * 4 + j;
      if (gn >= N) continue;
      Cb[(long long)gm * N + gn] = alpha * acc[i][j];
    }
  }
}

// ---------------- Wm = z @ O3, written transposed bf16 WmT[bh][d][k] -------
__global__ __launch_bounds__(256)
void wm_gemm(const float* __restrict__ Z, const float* __restrict__ O3,
             unsigned short* __restrict__ WmT) {
  const int batch = blockIdx.y;
  const int m0 = blockIdx.x * 64;
  const float* A = Z + (long long)batch * 65536;
  const float* B = O3 + (long long)batch * LM * DH;
  __shared__ float As[16][68];
  __shared__ float Bs[16][68];
  const int tid = threadIdx.x, tx = tid & 15, ty = tid >> 4;
  float acc[4][4] = {};
  for (int k0 = 0; k0 < 256; k0 += 16) {
    {
      int k = tid & 15, mB = tid >> 4;
#pragma unroll
      for (int i = 0; i < 4; i++) {
        int m = mB + i * 16;
        As[k][m] = A[(long long)(m0 + m) * 256 + k0 + k];
      }
    }
    {
      int n = tid & 63, kB = tid >> 6;
#pragma unroll
      for (int i = 0; i < 4; i++) {
        int k = kB + i * 4;
        Bs[k][n] = B[(long long)(k0 + k) * DH + n];
      }
    }
    __syncthreads();
#pragma unroll
    for (int k = 0; k < 16; k++) {
      float a[4], b[4];
#pragma unroll
      for (int i = 0; i < 4; i++) a[i] = As[k][ty * 4 + i];
#pragma unroll
      for (int j = 0; j < 4; j++) b[j] = Bs[k][tx * 4 + j];
#pragma unroll
      for (int i = 0; i < 4; i++)
#pragma unroll
        for (int j = 0; j < 4; j++) acc[i][j] = fmaf(a[i], b[j], acc[i][j]);
    }
    __syncthreads();
  }
#pragma unroll
  for (int i = 0; i < 4; i++)
#pragma unroll
    for (int j = 0; j < 4; j++)
      WmT[((long long)batch * DH + tx * 4 + j) * LM + m0 + ty * 4 + i] =
          f2bf(acc[i][j]);
}

// ---------------- row layernorm over 512 -> bf16 ----------------
__global__ __launch_bounds__(256)
void layernorm_rows_bf16(const float* __restrict__ X, const float* __restrict__ g,
                         const float* __restrict__ bt,
                         unsigned short* __restrict__ Y) {
  __shared__ float sm[4];
  long long r = blockIdx.x;
  const float* x = X + r * DIM;
  int t = threadIdx.x;
  float v0 = x[t], v1 = x[t + 256];
  float mu = blockReduceSum256(v0 + v1, sm) * (1.f / DIM);
  float d0 = v0 - mu, d1 = v1 - mu;
  float var = blockReduceSum256(d0 * d0 + d1 * d1, sm) * (1.f / DIM);
  float rs = 1.0f / sqrtf(var + 1e-5f);
  unsigned short* y = Y + r * DIM;
  y[t] = f2bf(d0 * rs * g[t] + bt[t]);
  y[t + 256] = f2bf(d1 * rs * g[t + 256] + bt[t + 256]);
}

// ---------------- landmark means from bf16 q,k ----------------
__global__ __launch_bounds__(64)
void landmarks_k(const unsigned short* __restrict__ q,
                 const unsigned short* __restrict__ k,
                 float* __restrict__ ql, float* __restrict__ kl,
                 unsigned short* __restrict__ qlb,
                 unsigned short* __restrict__ klb) {
  int bh = blockIdx.x >> 8, i = blockIdx.x & 255, d = threadIdx.x;
  long long base = ((long long)bh * NF + i * 32) * DH + d;
  float sq = 0.f, sk = 0.f;
#pragma unroll 4
  for (int l = 0; l < 32; l++) {
    sq += bf2f(q[base + (long long)l * DH]);
    sk += bf2f(k[base + (long long)l * DH]);
  }
  long long o = ((long long)bh * LM + i) * DH + d;
  float mq = sq * (1.f / 32.f), mk = sk * (1.f / 32.f);
  ql[o] = mq; kl[o] = mk;
  qlb[o] = f2bf(mq); klb[o] = f2bf(mk);
}

// ---------------- sim2 + row softmax -> attn2 (fp32 + bf16) ----------------
__global__ __launch_bounds__(256)
void sim2_softmax(const float* __restrict__ ql, const float* __restrict__ kl,
                  float* __restrict__ a2, unsigned short* __restrict__ a2b) {
  __shared__ float qs[64];
  __shared__ float sm[4];
  int bh = blockIdx.x >> 8, i = blockIdx.x & 255, t = threadIdx.x;
  if (t < 64) qs[t] = ql[((long long)bh * LM + i) * DH + t];
  __syncthreads();
  const float* krow = kl + (long long)bh * LM * DH + (long long)t * DH;
  float s = 0.f;
#pragma unroll
  for (int d = 0; d < 64; d++) s += qs[d] * krow[d];
  float m = blockReduceMax256(s, sm);
  float e = expf(s - m);
  float sum = blockReduceSum256(e, sm);
  long long off = ((long long)bh * LM + i) * LM + t;
  float v = e / sum;
  a2[off] = v;
  a2b[off] = f2bf(v);
}

// ---------------- pinv global scale reduction (col sums only) --------------
// softmax rows sum to exactly 1 -> the ref's row-sum max factor == 1.
__global__ __launch_bounds__(256)
void pinv_reduce(const float* __restrict__ a2, unsigned* __restrict__ red) {
  __shared__ float sm[4];
  int bh = blockIdx.x, t = threadIdx.x;
  const float* A = a2 + (long long)bh * LM * LM;
  float cs = 0.f;
  for (int i = 0; i < 256; i++) cs += fabsf(A[i * 256 + t]);
  float cm = blockReduceMax256(cs, sm);
  if (t == 0) atomicMax(&red[1], __float_as_uint(cm));
}

// ---------------- depthwise conv residual -> bf16 scattered ----------------
__global__ __launch_bounds__(256)
void conv_res_bf16(const unsigned short* __restrict__ vt,
                   const float* __restrict__ cw,
                   unsigned short* __restrict__ out) {
  int bh = blockIdx.x >> 6, tile = blockIdx.x & 63;
  int b = bh >> 3, hh = bh & 7;
  int t = threadIdx.x;
  int d = t & 63, pg = t >> 6;
  float wr[33];
#pragma unroll
  for (int kk = 0; kk < 33; kk++) wr[kk] = cw[hh * 33 + kk];
  const unsigned short* src = &vt[((long long)bh * DH + d) * NF];
  int base = tile * 128 + pg * 32;
  int n0 = base - 16;
  float win[64];
#pragma unroll
  for (int jj = 0; jj < 8; jj++) {
    int c = n0 + jj * 8;
    if (c >= 0 && c + 7 < NF) {
      short8 v = *(const short8*)&src[c];
#pragma unroll
      for (int j = 0; j < 8; j++)
        win[jj * 8 + j] = bf2f((unsigned short)v[j]);
    } else {
#pragma unroll
      for (int j = 0; j < 8; j++) {
        int nn = c + j;
        win[jj * 8 + j] = (nn >= 0 && nn < NF) ? bf2f(src[nn]) : 0.f;
      }
    }
  }
  unsigned short* dst = &out[((long long)(b * NF + base)) * DIM + hh * DH + d];
#pragma unroll
  for (int p = 0; p < 32; p++) {
    float s = 0.f;
#pragma unroll
    for (int kk = 0; kk < 33; kk++) s = fmaf(wr[kk], win[p + kk], s);
    dst[(long long)p * DIM] = f2bf(s);
  }
}

// ---------------- final LN(row0) @ w2 + b2 ----------------
__global__ __launch_bounds__(256)
void final_head(const float* __restrict__ X, const float* __restrict__ g,
                const float* __restrict__ bt, const float* __restrict__ w2,
                const float* __restrict__ b2, float* __restrict__ out) {
  __shared__ float sm[4];
  int b = blockIdx.x, t = threadIdx.x;
  const float* row = X + (long long)b * NF * DIM;
  float v0 = row[t], v1 = row[t + 256];
  float mu = blockReduceSum256(v0 + v1, sm) * (1.f / DIM);
  float d0 = v0 - mu, d1 = v1 - mu;
  float var = blockReduceSum256(d0 * d0 + d1 * d1, sm) * (1.f / DIM);
  float rs = 1.0f / sqrtf(var + 1e-5f);
  float y0 = d0 * rs * g[t] + bt[t];
  float y1 = d1 * rs * g[t + 256] + bt[t + 256];
  float l0 = y0 * w2[t * 2 + 0] + y1 * w2[(t + 256) * 2 + 0];
  float l1 = y0 * w2[t * 2 + 1] + y1 * w2[(t + 256) * 2 + 1];
  l0 = blockReduceSum256(l0, sm);
  l1 = blockReduceSum256(l1, sm);
  if (t == 0) {
    out[b * 2 + 0] = l0 + b2[0];
    out[b * 2 + 1] = l1 + b2[1];
  }
}

extern "C" void kernel_launch(void* const* d_in, const int* in_sizes, int n_in,
                              void* d_out, int out_size, void* d_ws,
                              size_t ws_size, hipStream_t stream) {
  const float* h      = (const float*)d_in[0];
  const float* w1     = (const float*)d_in[1];
  const float* b1     = (const float*)d_in[2];
  const float* cls    = (const float*)d_in[3];
  const float* ln_g   = (const float*)d_in[4];
  const float* ln_b   = (const float*)d_in[5];
  const float* w_qkv  = (const float*)d_in[6];
  const float* w_out  = (const float*)d_in[7];
  const float* b_out  = (const float*)d_in[8];
  const float* conv_w = (const float*)d_in[9];
  const float* fn_g   = (const float*)d_in[10];
  const float* fn_b   = (const float*)d_in[11];
  const float* w2     = (const float*)d_in[12];
  const float* b2     = (const float*)d_in[13];

  float* ws = (float*)d_ws;
  const long long XSZ = (long long)2 * NF * DIM;      // 8388608
  const long long QSZ = (long long)BHN * NF * DH;     // 8388608
  float* X  = ws;                                     // 8.4M f
  unsigned short* STAGE = (unsigned short*)(X + XSZ); // staging us region
  unsigned short* HB   = STAGE;                 // embed bf16
  unsigned short* XNB1 = STAGE;                 // LN out bf16
  unsigned short* XNB2 = STAGE;                 // attn out bf16 (XNB1 dead)
  unsigned short* VB   = STAGE + XSZ;           // V row-major temp
  unsigned short* XNC  = STAGE + XSZ;           // conv bf16 (VB dead)
  unsigned short* QB = STAGE + 2 * XSZ;
  unsigned short* KB = QB + QSZ;
  unsigned short* VT = KB + QSZ;                // d-major
  float* QL = (float*)(VT + QSZ);
  float* KL = QL + 262144;
  unsigned short* QLB = (unsigned short*)(KL + 262144);
  unsigned short* KLB = QLB + 262144;
  float* A2 = (float*)(KLB + 262144);           // fp32 attn2 (reduce + it5)
  float* ZA = A2 + 1048576;                     // final fp32 z (wm_gemm)
  float* ZB = ZA + 1048576;                     // z4 fp32 (it5 input)
  float* P  = ZB + 1048576;                     // it5 fp32 temps
  float* T1 = P + 1048576;
  float* T2 = T1 + 1048576;
  float* Mpart = T2 + 1048576;                  // 65536 f (unused slot)
  float* Lpart = Mpart + 65536;                 // 65536 f
  float* O3 = Lpart + 65536;                    // 262144 f
  unsigned short* WmB = (unsigned short*)(O3 + 262144);  // 262144 us
  unsigned* RED = (unsigned*)(WmB + 262144);    // [unused, colmax, pad, pad]
  unsigned short* WT = (unsigned short*)(RED + 4);
  unsigned short* W1T = WT;                     // 524288 us
  unsigned short* WQ0 = W1T + 524288;           // 786432
  unsigned short* WQ1 = WQ0 + 786432;           // 786432
  unsigned short* WO0 = WQ1 + 786432;           // 262144
  unsigned short* WO1 = WO0 + 262144;           // 262144

  // Aliases with disjoint liveness inside the VB/XNC slot (16.77 MB):
  //   VB (qkv->vt) -> A2B (sim2->pinv it4 S1) -> Opart (attn3->merge) -> XNC
  unsigned short* A2B = VB;                     // bf16 attn2 (pinv A-operand)
  float* Opart = (float*)VB;                    // 16*16*256*64 f = 16.77 MB
  // bf16 pinv buffers alias fp32 it5 temps (live only during it0..4):
  unsigned short* Zan = (unsigned short*)P;     // z even-iter (normal)
  unsigned short* Zat = Zan + 1048576;          // z even-iter (transposed)
  unsigned short* Zbn = (unsigned short*)ZB;    // z odd-iter
  unsigned short* Zbt = Zbn + 1048576;
  unsigned short* Pn  = (unsigned short*)T1;    // P = A2@z
  unsigned short* Pt  = Pn + 1048576;
  unsigned short* T1t = (unsigned short*)T2;    // bracket temps (B-operand only)
  unsigned short* T2t = T1t + 1048576;

  // ---- prologue: cls, h cast, all weight transposes, embed ----
  write_cls<<<4, 256, 0, stream>>>(cls, X);
  cvt_bf16<<<16382, 256, 0, stream>>>(h, HB, (long long)16382 * 1024);
  cvt_transpose<<<dim3(512 / 32, 1024 / 32), 256, 0, stream>>>(w1, W1T, 1024, 512);
  cvt_transpose<<<dim3(1536 / 32, 512 / 32), 256, 0, stream>>>(w_qkv, WQ0, 512, 1536);
  cvt_transpose<<<dim3(1536 / 32, 512 / 32), 256, 0, stream>>>(
      w_qkv + (long long)DIM * 1536, WQ1, 512, 1536);
  cvt_transpose<<<dim3(512 / 32, 512 / 32), 256, 0, stream>>>(w_out, WO0, 512, 512);
  cvt_transpose<<<dim3(512 / 32, 512 / 32), 256, 0, stream>>>(
      w_out + (long long)DIM * DIM, WO1, 512, 512);
  gemm_mfma<0, 3><<<dim3(2, 128), 512, 0, stream>>>(HB, W1T, b1, X, nullptr,
                                                    nullptr, 16382, 512, 1024,
                                                    MG_RELU | MG_BIAS, 1);

  for (int L = 0; L < 2; L++) {
    layernorm_rows_bf16<<<2 * NF, 256, 0, stream>>>(X, ln_g + L * DIM,
                                                    ln_b + L * DIM, XNB1);
    gemm_mfma<0, 2><<<dim3(6, 128), 512, 0, stream>>>(XNB1, L ? WQ1 : WQ0,
                                                      nullptr, nullptr, QB, VB,
                                                      16384, 1536, 512, 0, 2);
    vt_transpose<<<BHN * 128, 256, 0, stream>>>(VB, VT);

    landmarks_k<<<BHN * LM, 64, 0, stream>>>(QB, KB, QL, KL, QLB, KLB);
    sim2_softmax<<<BHN * LM, 256, 0, stream>>>(QL, KL, A2, A2B);
    hipMemsetAsync(RED, 0, 16, stream);
    pinv_reduce<<<BHN, 256, 0, stream>>>(A2, RED);
    zinit<<<4096, 256, 0, stream>>>(A2, RED, Zan, Zat);
    for (int it = 0; it < 5; it++) {  // bf16 iterations (NS self-corrects)
      const unsigned short* zcn = (it & 1) ? Zbn : Zan;
      const unsigned short* zct = (it & 1) ? Zbt : Zat;
      unsigned short* znn = (it & 1) ? Zan : Zbn;
      unsigned short* znt = (it & 1) ? Zat : Zbt;
      // P = A2 @ z
      pinv_bf<<<dim3(8, 8, BHN), 256, 0, stream>>>(
          A2B, zct, Pn, Pt, nullptr, 1.f, 0.f, 1.f, PV_CN | PV_CT);
      // T1 = 7P - P@P
      pinv_bf<<<dim3(8, 8, BHN), 256, 0, stream>>>(
          Pn, Pt, nullptr, T1t, nullptr, 1.f, 7.f, -1.f, PV_CT | PV_ID);
      // T2 = 15P - P@T1
      pinv_bf<<<dim3(8, 8, BHN), 256, 0, stream>>>(
          Pn, T1t, nullptr, T2t, nullptr, 1.f, 15.f, -1.f, PV_CT | PV_ID);
      // zn = 0.25*(13z - z@T2); it==4 writes fp32 z4 for the fp32 iteration
      if (it < 4)
        pinv_bf<<<dim3(8, 8, BHN), 256, 0, stream>>>(
            zcn, T2t, znn, znt, nullptr, 0.25f, 13.f, -1.f,
            PV_CN | PV_CT | PV_ID);
      else
        pinv_bf<<<dim3(8, 8, BHN), 256, 0, stream>>>(
            zcn, T2t, nullptr, nullptr, ZB, 0.25f, 13.f, -1.f, PV_CF | PV_ID);
    }
    // final iteration fp32
    bgemm<<<dim3(4, 4, BHN), 256, 0, stream>>>(A2, ZB, P, 256, 256, 256,
                                               65536, 65536, 65536, 1.f, 0.f, 0);
    bgemm<<<dim3(4, 4, BHN), 256, 0, stream>>>(P, P, T1, 256, 256, 256,
                                               65536, 65536, 65536, 1.f, 7.f,
                                               BG_BIDENT);
    bgemm<<<dim3(4, 4, BHN), 256, 0, stream>>>(P, T1, T2, 256, 256, 256,
                                               65536, 65536, 65536, 1.f, 15.f,
                                               BG_BIDENT);
    bgemm<<<dim3(4, 4, BHN), 256, 0, stream>>>(ZB, T2, ZA, 256, 256, 256,
                                               65536, 65536, 65536, 0.25f,
                                               13.f, BG_BIDENT);
    // final z in ZA

    // ---- fused attn3: LDS-resident chunks; plain (O,L) partials -> O3 ----
    flash_attn3<<<dim3(16, BHN), 512, 0, stream>>>(QLB, KB, VT, Opart, Lpart);
    attn3_merge<<<1024, 256, 0, stream>>>(Opart, Lpart, O3);

    // WmT(bf16) = (z @ O3)^T
    wm_gemm<<<dim3(4, BHN), 256, 0, stream>>>(ZA, O3, WmB);

    // conv residual (bf16) into XNC (overwrites dead Opart)
    conv_res_bf16<<<BHN * 64, 256, 0, stream>>>(VT, conv_w + L * 264, XNC);

    // ---- fused attn1 (LDS-resident K+Wm): XNB2 = bf16(conv + attn1@Wm) ----
    flash_attn1<<<dim3(32, BHN), 512, 0, stream>>>(QB, KLB, WmB, XNC, XNB2);

    // ---- X += XNB2 @ w_out + b_out ----
    gemm_mfma<1, 3><<<dim3(2, 128), 512, 0, stream>>>(XNB2, L ? WO1 : WO0,
                                                      b_out + L * DIM, X,
                                                      nullptr, nullptr, 16384,
                                                      512, 512,
                                                      MG_ADDC | MG_BIAS, 0);
  }
  final_head<<<2, 256, 0, stream>>>(X, fn_g, fn_b, w2, b2, (float*)d_out);
}